// Round 2
// baseline (7383.912 us; speedup 1.0000x reference)
//
#include <hip/hip_runtime.h>
#include <math.h>

#define NN 50000
#define EE 400000
#define EMBD 128
#define KIN 288
#define NITERS 2
#define EPSV 1e-5f

// ---------------- zero / setup kernels ----------------

__global__ void k_zeroi(int* __restrict__ p, int n) {
  for (int i = blockIdx.x * blockDim.x + threadIdx.x; i < n;
       i += gridDim.x * blockDim.x)
    p[i] = 0;
}

__global__ void k_zerof4(float* __restrict__ p, int n4) {
  float4 z; z.x = z.y = z.z = z.w = 0.f;
  for (int i = blockIdx.x * blockDim.x + threadIdx.x; i < n4;
       i += gridDim.x * blockDim.x)
    ((float4*)p)[i] = z;
}

__global__ void k_detect(const long long* __restrict__ e64, int* __restrict__ flag) {
  __shared__ int ok;
  if (threadIdx.x == 0) ok = 1;
  __syncthreads();
  for (int i = threadIdx.x; i < 4096; i += blockDim.x) {
    const long long v = e64[i];
    if (v < 0 || v >= NN) atomicAnd(&ok, 0);
  }
  __syncthreads();
  if (threadIdx.x == 0) *flag = ok;
}

__global__ void k_convert(const void* __restrict__ edges, const int* __restrict__ flag,
                          int* __restrict__ src, int* __restrict__ dst) {
  const int is64 = *flag;
  for (int i = blockIdx.x * blockDim.x + threadIdx.x; i < 2 * EE;
       i += gridDim.x * blockDim.x) {
    const int v = is64 ? (int)((const long long*)edges)[i] : ((const int*)edges)[i];
    if (i < EE) src[i] = v; else dst[i - EE] = v;
  }
}

__global__ void k_count(const int* __restrict__ src, const int* __restrict__ dst,
                        int* __restrict__ degp, int* __restrict__ degc) {
  for (int e = blockIdx.x * blockDim.x + threadIdx.x; e < EE;
       e += gridDim.x * blockDim.x) {
    atomicAdd(&degp[dst[e]], 1);
    atomicAdd(&degc[src[e]], 1);
  }
}

__global__ void k_dinv(const int* __restrict__ dp, const int* __restrict__ dc,
                       float* __restrict__ ip, float* __restrict__ ic) {
  for (int n = blockIdx.x * blockDim.x + threadIdx.x; n < NN;
       n += gridDim.x * blockDim.x) {
    ip[n] = dp[n] ? 1.f / (float)dp[n] : 0.f;
    ic[n] = dc[n] ? 1.f / (float)dc[n] : 0.f;
  }
}

__global__ __launch_bounds__(1024) void k_scan(
    const int* __restrict__ degp, const int* __restrict__ degc,
    int* __restrict__ offp, int* __restrict__ offc) {
  const int* deg = blockIdx.x ? degc : degp;
  int* off = blockIdx.x ? offc : offp;
  __shared__ int sh[1024];
  const int t = threadIdx.x;
  int running = 0;
  for (int base = 0; base < NN; base += 1024) {
    const int v = (base + t < NN) ? deg[base + t] : 0;
    sh[t] = v;
    __syncthreads();
    for (int o = 1; o < 1024; o <<= 1) {
      const int y = (t >= o) ? sh[t - o] : 0;
      __syncthreads();
      sh[t] += y;
      __syncthreads();
    }
    if (base + t < NN) off[base + t] = running + sh[t] - v;
    running += sh[1023];
    __syncthreads();
  }
  if (t == 0) off[NN] = running;
}

__global__ void k_copycur(const int* __restrict__ offp, const int* __restrict__ offc,
                          int* __restrict__ curp, int* __restrict__ curc) {
  for (int i = blockIdx.x * blockDim.x + threadIdx.x; i < NN;
       i += gridDim.x * blockDim.x) {
    curp[i] = offp[i];
    curc[i] = offc[i];
  }
}

__global__ void k_scatter(const int* __restrict__ src, const int* __restrict__ dst,
                          int* __restrict__ curp, int* __restrict__ curc,
                          int* __restrict__ lstp, int* __restrict__ lstc,
                          int* __restrict__ ownp, int* __restrict__ ownc) {
  for (int e = blockIdx.x * blockDim.x + threadIdx.x; e < EE;
       e += gridDim.x * blockDim.x) {
    const int dp = dst[e];
    const int pp = atomicAdd(&curp[dp], 1);
    lstp[pp] = e;
    ownp[pp] = dp;
    const int sc = src[e];
    const int pc = atomicAdd(&curc[sc], 1);
    lstc[pc] = e;
    ownc[pc] = sc;
  }
}

__global__ void k_copy4(const float* __restrict__ in, float* __restrict__ out, int n4) {
  for (int i = blockIdx.x * blockDim.x + threadIdx.x; i < n4;
       i += gridDim.x * blockDim.x)
    ((float4*)out)[i] = ((const float4*)in)[i];
}

// ---------------- GEMM core ----------------
// 32 rows x 128 cols per block, 256 threads, each thread 4 rows x 4 cols.

template <int STRIDE, int KTOT>
__device__ __forceinline__ void gemm_k(const float* __restrict__ inb,
                                       float (*w_t)[EMBD],
                                       const float* __restrict__ W,
                                       const int t, const int rg, const int cg,
                                       float acc[4][4]) {
#pragma unroll 1
  for (int kc = 0; kc < KTOT; kc += 16) {
    __syncthreads();
    {
      const float4* wg = (const float4*)(W + (size_t)kc * EMBD);
      float4* wl = (float4*)&w_t[0][0];
      wl[t] = wg[t];
      wl[t + 256] = wg[t + 256];
    }
    __syncthreads();
#pragma unroll
    for (int k4 = 0; k4 < 4; ++k4) {
      float a[4][4], w[4][4];
#pragma unroll
      for (int rr = 0; rr < 4; ++rr) {
        const float4 av = *(const float4*)&inb[(rg * 4 + rr) * STRIDE + kc + k4 * 4];
        a[rr][0] = av.x; a[rr][1] = av.y; a[rr][2] = av.z; a[rr][3] = av.w;
      }
#pragma unroll
      for (int kk = 0; kk < 4; ++kk) {
        const float4 wv = ((const float4*)&w_t[k4 * 4 + kk][0])[cg];
        w[kk][0] = wv.x; w[kk][1] = wv.y; w[kk][2] = wv.z; w[kk][3] = wv.w;
      }
#pragma unroll
      for (int rr = 0; rr < 4; ++rr)
#pragma unroll
        for (int kk = 0; kk < 4; ++kk)
#pragma unroll
          for (int cc = 0; cc < 4; ++cc)
            acc[rr][cc] = fmaf(a[rr][kk], w[kk][cc], acc[rr][cc]);
    }
  }
}

__device__ __forceinline__ void stats_epilogue(const float acc[4][4],
                                               float (*red)[EMBD],
                                               float* __restrict__ statbase,
                                               const int t, const int rg, const int cg,
                                               const int row0, const int rlim) {
  float s[4] = {0.f, 0.f, 0.f, 0.f}, sq[4] = {0.f, 0.f, 0.f, 0.f};
#pragma unroll
  for (int rr = 0; rr < 4; ++rr) {
    if (row0 + rg * 4 + rr < rlim) {
#pragma unroll
      for (int cc = 0; cc < 4; ++cc) {
        const float v = acc[rr][cc];
        s[cc] += v;
        sq[cc] += v * v;
      }
    }
  }
#pragma unroll
  for (int cc = 0; cc < 4; ++cc) {
    atomicAdd(&red[0][cg * 4 + cc], s[cc]);
    atomicAdd(&red[1][cg * 4 + cc], sq[cc]);
  }
  __syncthreads();
  if (t < EMBD) {
    atomicAdd(&statbase[t], red[0][t]);
    atomicAdd(&statbase[EMBD + t], red[1][t]);
  }
}

// ---------------- edge pipeline ----------------
// stat layout (floats): [0,128) sum1  [128,256) sumsq1  [256,384) sc1 [384,512) sh1
//                       [512,640) sum2 [640,768) sumsq2 [768,896) sc2 [896,1024) sh2
// PASS 0: GEMM1 -> stats1.  PASS 1: GEMM1+BN1relu+GEMM2 -> stats2.
// PASS 2 (CSR order): recompute both, BN2relu * dinv, segmented sum into agg.

template <int PASS>
__global__ __launch_bounds__(256) void k_edge(
    const float* __restrict__ x, const int* __restrict__ idx_i,
    const int* __restrict__ idx_j, const float* __restrict__ ea,
    const float* __restrict__ W1, const float* __restrict__ W2,
    float* __restrict__ stat, const int* __restrict__ lst,
    const int* __restrict__ own, const float* __restrict__ dinv,
    float* __restrict__ agg) {
  __shared__ float in_t[32 * KIN];
  __shared__ float w_t[16][EMBD];
  __shared__ float red[2][EMBD];
  __shared__ int ownsh[32];
  __shared__ float dish[32];
  const int t = threadIdx.x;
  const int s0 = blockIdx.x * 32;
  {
    const int r = t >> 3, sub = t & 7;
    const int e = (PASS == 2) ? lst[s0 + r] : (s0 + r);
    const int i = idx_i[e], j = idx_j[e];
    const float4* xi = (const float4*)(x + (size_t)i * EMBD);
    const float4* xj = (const float4*)(x + (size_t)j * EMBD);
    const float4* eap = (const float4*)(ea + (size_t)e * 32);
    float4* row = (float4*)&in_t[r * KIN];
#pragma unroll
    for (int q = 0; q < 9; ++q) {
      const int f4 = sub + q * 8;
      float4 v;
      if (f4 < 32) v = xi[f4];
      else if (f4 < 64) v = xj[f4 - 32];
      else v = eap[f4 - 64];
      row[f4] = v;
    }
  }
  if (PASS == 2) {
    if (t < 32) {
      const int n = own[s0 + t];
      ownsh[t] = n;
      dish[t] = dinv[n];
    }
  } else {
    if (t < EMBD) { red[0][t] = 0.f; red[1][t] = 0.f; }
  }
  const int rg = t >> 5, cg = t & 31;
  float acc[4][4] = {};
  gemm_k<KIN, KIN>(in_t, w_t, W1, t, rg, cg, acc);
  if (PASS == 0) {
    stats_epilogue(acc, red, stat, t, rg, cg, 0, 32);
    return;
  }
  // BN1 + ReLU -> LDS cols [0,128)
  const float4 sc1 = ((const float4*)(stat + 256))[cg];
  const float4 sh1 = ((const float4*)(stat + 384))[cg];
  __syncthreads();
#pragma unroll
  for (int rr = 0; rr < 4; ++rr) {
    float4 v;
    v.x = fmaxf(fmaf(acc[rr][0], sc1.x, sh1.x), 0.f);
    v.y = fmaxf(fmaf(acc[rr][1], sc1.y, sh1.y), 0.f);
    v.z = fmaxf(fmaf(acc[rr][2], sc1.z, sh1.z), 0.f);
    v.w = fmaxf(fmaf(acc[rr][3], sc1.w, sh1.w), 0.f);
    *(float4*)&in_t[(rg * 4 + rr) * KIN + cg * 4] = v;
  }
  float acc2[4][4] = {};
  gemm_k<KIN, EMBD>(in_t, w_t, W2, t, rg, cg, acc2);
  if (PASS == 1) {
    stats_epilogue(acc2, red, stat + 512, t, rg, cg, 0, 32);
    return;
  }
  // PASS 2: BN2 + ReLU, scale by dinv, segmented sum into agg
  const float4 sc2 = ((const float4*)(stat + 768))[cg];
  const float4 sh2 = ((const float4*)(stat + 896))[cg];
  __syncthreads();
#pragma unroll
  for (int rr = 0; rr < 4; ++rr) {
    const int row = rg * 4 + rr;
    const float d = dish[row];
    float4 v;
    v.x = fmaxf(fmaf(acc2[rr][0], sc2.x, sh2.x), 0.f) * d;
    v.y = fmaxf(fmaf(acc2[rr][1], sc2.y, sh2.y), 0.f) * d;
    v.z = fmaxf(fmaf(acc2[rr][2], sc2.z, sh2.z), 0.f) * d;
    v.w = fmaxf(fmaf(acc2[rr][3], sc2.w, sh2.w), 0.f) * d;
    *(float4*)&in_t[row * KIN + cg * 4] = v;
  }
  __syncthreads();
  const int col = t & 127;
  const int r0 = (t >> 7) * 16;
  int cur = ownsh[r0];
  float run = 0.f;
#pragma unroll 1
  for (int rr = r0; rr < r0 + 16; ++rr) {
    const int o = ownsh[rr];
    if (o != cur) {
      atomicAdd(&agg[(size_t)cur * EMBD + col], run);
      run = 0.f;
      cur = o;
    }
    run += in_t[rr * KIN + col];
  }
  atomicAdd(&agg[(size_t)cur * EMBD + col], run);
}

// ---------------- node update ----------------
// Z = (nodes + agg) @ fW, written back into agg (in-place safe: each block
// reads only its own 32 rows into LDS before writing them). Stats -> stat[0..).

__global__ __launch_bounds__(256) void k_node(
    const float* __restrict__ nd, float* __restrict__ ag,
    const float* __restrict__ W, float* __restrict__ stat) {
  __shared__ float in_t[32 * EMBD];
  __shared__ float w_t[16][EMBD];
  __shared__ float red[2][EMBD];
  const int t = threadIdx.x;
  const int n0 = blockIdx.x * 32;
  {
    const int r = t >> 3, sub = t & 7;
    const int row = n0 + r;
    float4* drow = (float4*)&in_t[r * EMBD];
    if (row < NN) {
      const float4* a = (const float4*)(nd + (size_t)row * EMBD);
      const float4* b = (const float4*)(ag + (size_t)row * EMBD);
#pragma unroll
      for (int q = 0; q < 4; ++q) {
        const int f4 = sub + q * 8;
        float4 va = a[f4];
        const float4 vb = b[f4];
        va.x += vb.x; va.y += vb.y; va.z += vb.z; va.w += vb.w;
        drow[f4] = va;
      }
    } else {
      float4 z; z.x = z.y = z.z = z.w = 0.f;
#pragma unroll
      for (int q = 0; q < 4; ++q) drow[sub + q * 8] = z;
    }
  }
  if (t < EMBD) { red[0][t] = 0.f; red[1][t] = 0.f; }
  const int rg = t >> 5, cg = t & 31;
  float acc[4][4] = {};
  gemm_k<EMBD, EMBD>(in_t, w_t, W, t, rg, cg, acc);
  float s[4] = {0.f, 0.f, 0.f, 0.f}, sq[4] = {0.f, 0.f, 0.f, 0.f};
#pragma unroll
  for (int rr = 0; rr < 4; ++rr) {
    const int row = n0 + rg * 4 + rr;
    if (row < NN) {
      float4 v;
      v.x = acc[rr][0]; v.y = acc[rr][1]; v.z = acc[rr][2]; v.w = acc[rr][3];
      ((float4*)(ag + (size_t)row * EMBD))[cg] = v;
      s[0] += v.x; s[1] += v.y; s[2] += v.z; s[3] += v.w;
      sq[0] += v.x * v.x; sq[1] += v.y * v.y;
      sq[2] += v.z * v.z; sq[3] += v.w * v.w;
    }
  }
#pragma unroll
  for (int cc = 0; cc < 4; ++cc) {
    atomicAdd(&red[0][cg * 4 + cc], s[cc]);
    atomicAdd(&red[1][cg * 4 + cc], sq[cc]);
  }
  __syncthreads();
  if (t < EMBD) {
    atomicAdd(&stat[t], red[0][t]);
    atomicAdd(&stat[EMBD + t], red[1][t]);
  }
}

// ---------------- BN finalize / node residual ----------------

__global__ void k_finalize(float* __restrict__ statbase, const float* __restrict__ g,
                           const float* __restrict__ be, float cnt) {
  const int t = threadIdx.x;
  if (t < EMBD) {
    const float s = statbase[t], sq = statbase[EMBD + t];
    const float m = s / cnt;
    float v = sq / cnt - m * m;
    v = fmaxf(v, 0.f);
    const float rs = rsqrtf(v + EPSV);
    const float sc = g[t] * rs;
    statbase[256 + t] = sc;
    statbase[384 + t] = be[t] - m * sc;
    statbase[t] = 0.f;
    statbase[EMBD + t] = 0.f;
  }
}

__global__ void k_update(float* __restrict__ nd, const float* __restrict__ Z,
                         const float* __restrict__ scale,
                         const float* __restrict__ shift) {
  const int total = NN * EMBD / 4;
  for (int i = blockIdx.x * blockDim.x + threadIdx.x; i < total;
       i += gridDim.x * blockDim.x) {
    const int c4 = i & 31;
    const float4 v = ((const float4*)Z)[i];
    const float4 sc = ((const float4*)scale)[c4];
    const float4 sh = ((const float4*)shift)[c4];
    float4 nv = ((float4*)nd)[i];
    nv.x += fmaxf(fmaf(v.x, sc.x, sh.x), 0.f);
    nv.y += fmaxf(fmaf(v.y, sc.y, sh.y), 0.f);
    nv.z += fmaxf(fmaf(v.z, sc.z, sh.z), 0.f);
    nv.w += fmaxf(fmaf(v.w, sc.w, sh.w), 0.f);
    ((float4*)nd)[i] = nv;
  }
}

// ---------------- launch ----------------

extern "C" void kernel_launch(void* const* d_in, const int* in_sizes, int n_in,
                              void* d_out, int out_size, void* d_ws, size_t ws_size,
                              hipStream_t stream) {
  const float* in_nodes = (const float*)d_in[0];
  const void* edges = d_in[1];
  const float* ea = (const float*)d_in[2];
  const float* fW = (const float*)d_in[3];
  const float* fg = (const float*)d_in[5];
  const float* fbe = (const float*)d_in[6];
  const float* p_[8];
  const float* c_[8];
  for (int i = 0; i < 8; ++i) {
    p_[i] = (const float*)d_in[7 + i];
    c_[i] = (const float*)d_in[15 + i];
  }
  float* nodes = (float*)d_out;  // nodes live in d_out

  char* base = (char*)d_ws;
  size_t cur = 0;
  auto take = [&](size_t bytes) -> void* {
    void* p = base + cur;
    cur = (cur + bytes + 255) & ~(size_t)255;
    return p;
  };
  float* agg = (float*)take((size_t)NN * EMBD * 4);  // 25.6 MB
  int* src = (int*)take(EE * 4);
  int* dst = (int*)take(EE * 4);
  int* lstp = (int*)take(EE * 4);
  int* lstc = (int*)take(EE * 4);
  int* ownp = (int*)take(EE * 4);
  int* ownc = (int*)take(EE * 4);
  int* offp = (int*)take((NN + 1) * 4);
  int* offc = (int*)take((NN + 1) * 4);
  int* curp = (int*)take(NN * 4);
  int* curc = (int*)take(NN * 4);
  float* dinvp = (float*)take(NN * 4);
  float* dinvc = (float*)take(NN * 4);
  float* stat = (float*)take(1024 * 4);
  int* flag = (int*)take(4);
  // total ~36.3 MB

  k_zeroi<<<64, 256, 0, stream>>>((int*)stat, 1024);
  k_zeroi<<<128, 256, 0, stream>>>(curp, NN);
  k_zeroi<<<128, 256, 0, stream>>>(curc, NN);
  k_detect<<<1, 256, 0, stream>>>((const long long*)edges, flag);
  k_convert<<<1024, 256, 0, stream>>>(edges, flag, src, dst);
  k_count<<<1024, 256, 0, stream>>>(src, dst, curp, curc);
  k_dinv<<<128, 256, 0, stream>>>(curp, curc, dinvp, dinvc);
  k_scan<<<2, 1024, 0, stream>>>(curp, curc, offp, offc);
  k_copycur<<<128, 256, 0, stream>>>(offp, offc, curp, curc);
  k_scatter<<<1024, 256, 0, stream>>>(src, dst, curp, curc, lstp, lstc, ownp, ownc);
  k_copy4<<<2048, 256, 0, stream>>>(in_nodes, nodes, NN * EMBD / 4);

  const int EB = EE / 32;           // 12500
  const int NB = (NN + 31) / 32;    // 1563

  for (int it = 0; it < NITERS; ++it) {
    k_zerof4<<<2048, 256, 0, stream>>>(agg, NN * EMBD / 4);
    // parent phase: idx_i = dst, idx_j = src
    k_edge<0><<<EB, 256, 0, stream>>>(nodes, dst, src, ea, p_[0], p_[4], stat,
                                      nullptr, nullptr, nullptr, nullptr);
    k_finalize<<<1, 128, 0, stream>>>(stat, p_[2], p_[3], (float)EE);
    k_edge<1><<<EB, 256, 0, stream>>>(nodes, dst, src, ea, p_[0], p_[4], stat,
                                      nullptr, nullptr, nullptr, nullptr);
    k_finalize<<<1, 128, 0, stream>>>(stat + 512, p_[6], p_[7], (float)EE);
    k_edge<2><<<EB, 256, 0, stream>>>(nodes, dst, src, ea, p_[0], p_[4], stat,
                                      lstp, ownp, dinvp, agg);
    // child phase: idx_i = src, idx_j = dst
    k_edge<0><<<EB, 256, 0, stream>>>(nodes, src, dst, ea, c_[0], c_[4], stat,
                                      nullptr, nullptr, nullptr, nullptr);
    k_finalize<<<1, 128, 0, stream>>>(stat, c_[2], c_[3], (float)EE);
    k_edge<1><<<EB, 256, 0, stream>>>(nodes, src, dst, ea, c_[0], c_[4], stat,
                                      nullptr, nullptr, nullptr, nullptr);
    k_finalize<<<1, 128, 0, stream>>>(stat + 512, c_[6], c_[7], (float)EE);
    k_edge<2><<<EB, 256, 0, stream>>>(nodes, src, dst, ea, c_[0], c_[4], stat,
                                      lstc, ownc, dinvc, agg);
    // node update: Z = (nodes + agg) @ fW -> agg; nodes += relu(bn(Z))
    k_node<<<NB, 256, 0, stream>>>(nodes, agg, fW, stat);
    k_finalize<<<1, 128, 0, stream>>>(stat, fg, fbe, (float)NN);
    k_update<<<2048, 256, 0, stream>>>(nodes, agg, stat + 256, stat + 384);
  }
}

// Round 3
// 3416.426 us; speedup vs baseline: 2.1613x; 2.1613x over previous
//
#include <hip/hip_runtime.h>
#include <math.h>

#define NN 50000
#define EE 400000
#define EMBD 128
#define KIN 288
#define NITERS 2
#define EPSV 1e-5f

typedef __attribute__((ext_vector_type(8))) short bf16x8;
typedef __attribute__((ext_vector_type(4))) float f32x4;

#define MFMA16(a, b, c) __builtin_amdgcn_mfma_f32_16x16x32_bf16(a, b, c, 0, 0, 0)

__device__ __forceinline__ unsigned short f2bf(float x) {
  unsigned int u = __float_as_uint(x);
  u += 0x7fffu + ((u >> 16) & 1u);
  return (unsigned short)(u >> 16);
}

// ---------------- zero / setup kernels ----------------

__global__ void k_zeroi(int* __restrict__ p, int n) {
  for (int i = blockIdx.x * blockDim.x + threadIdx.x; i < n;
       i += gridDim.x * blockDim.x)
    p[i] = 0;
}

__global__ void k_zerof4(float* __restrict__ p, int n4) {
  float4 z; z.x = z.y = z.z = z.w = 0.f;
  for (int i = blockIdx.x * blockDim.x + threadIdx.x; i < n4;
       i += gridDim.x * blockDim.x)
    ((float4*)p)[i] = z;
}

__global__ void k_detect(const long long* __restrict__ e64, int* __restrict__ flag) {
  __shared__ int ok;
  if (threadIdx.x == 0) ok = 1;
  __syncthreads();
  for (int i = threadIdx.x; i < 4096; i += blockDim.x) {
    const long long v = e64[i];
    if (v < 0 || v >= NN) atomicAnd(&ok, 0);
  }
  __syncthreads();
  if (threadIdx.x == 0) *flag = ok;
}

__global__ void k_convert(const void* __restrict__ edges, const int* __restrict__ flag,
                          int* __restrict__ src, int* __restrict__ dst) {
  const int is64 = *flag;
  for (int i = blockIdx.x * blockDim.x + threadIdx.x; i < 2 * EE;
       i += gridDim.x * blockDim.x) {
    const int v = is64 ? (int)((const long long*)edges)[i] : ((const int*)edges)[i];
    if (i < EE) src[i] = v; else dst[i - EE] = v;
  }
}

__global__ void k_count(const int* __restrict__ src, const int* __restrict__ dst,
                        int* __restrict__ degp, int* __restrict__ degc) {
  for (int e = blockIdx.x * blockDim.x + threadIdx.x; e < EE;
       e += gridDim.x * blockDim.x) {
    atomicAdd(&degp[dst[e]], 1);
    atomicAdd(&degc[src[e]], 1);
  }
}

__global__ void k_dinv(const int* __restrict__ dp, const int* __restrict__ dc,
                       float* __restrict__ ip, float* __restrict__ ic) {
  for (int n = blockIdx.x * blockDim.x + threadIdx.x; n < NN;
       n += gridDim.x * blockDim.x) {
    ip[n] = dp[n] ? 1.f / (float)dp[n] : 0.f;
    ic[n] = dc[n] ? 1.f / (float)dc[n] : 0.f;
  }
}

__global__ __launch_bounds__(1024) void k_scan(
    const int* __restrict__ degp, const int* __restrict__ degc,
    int* __restrict__ offp, int* __restrict__ offc) {
  const int* deg = blockIdx.x ? degc : degp;
  int* off = blockIdx.x ? offc : offp;
  __shared__ int sh[1024];
  const int t = threadIdx.x;
  int running = 0;
  for (int base = 0; base < NN; base += 1024) {
    const int v = (base + t < NN) ? deg[base + t] : 0;
    sh[t] = v;
    __syncthreads();
    for (int o = 1; o < 1024; o <<= 1) {
      const int y = (t >= o) ? sh[t - o] : 0;
      __syncthreads();
      sh[t] += y;
      __syncthreads();
    }
    if (base + t < NN) off[base + t] = running + sh[t] - v;
    running += sh[1023];
    __syncthreads();
  }
  if (t == 0) off[NN] = running;
}

__global__ void k_copycur(const int* __restrict__ offp, const int* __restrict__ offc,
                          int* __restrict__ curp, int* __restrict__ curc) {
  for (int i = blockIdx.x * blockDim.x + threadIdx.x; i < NN;
       i += gridDim.x * blockDim.x) {
    curp[i] = offp[i];
    curc[i] = offc[i];
  }
}

__global__ void k_scatter(const int* __restrict__ src, const int* __restrict__ dst,
                          int* __restrict__ curp, int* __restrict__ curc,
                          int* __restrict__ lstp, int* __restrict__ lstc,
                          int* __restrict__ ownp, int* __restrict__ ownc) {
  for (int e = blockIdx.x * blockDim.x + threadIdx.x; e < EE;
       e += gridDim.x * blockDim.x) {
    const int dp = dst[e];
    const int pp = atomicAdd(&curp[dp], 1);
    lstp[pp] = e;
    ownp[pp] = dp;
    const int sc = src[e];
    const int pc = atomicAdd(&curc[sc], 1);
    lstc[pc] = e;
    ownc[pc] = sc;
  }
}

// init nodes (f32 in d_out) + bf16 mirror
__global__ void k_initnodes(const float* __restrict__ in, float* __restrict__ nd,
                            unsigned short* __restrict__ xb) {
  const int tot = NN * EMBD / 4;
  for (int i = blockIdx.x * blockDim.x + threadIdx.x; i < tot;
       i += gridDim.x * blockDim.x) {
    const float4 v = ((const float4*)in)[i];
    ((float4*)nd)[i] = v;
    short4 b;
    b.x = (short)f2bf(v.x); b.y = (short)f2bf(v.y);
    b.z = (short)f2bf(v.z); b.w = (short)f2bf(v.w);
    *(short4*)&xb[(size_t)i * 4] = b;
  }
}

// W [K][128] f32 -> Wt [128][K] bf16
__global__ void k_prepW(const float* __restrict__ W, unsigned short* __restrict__ Wt,
                        int K) {
  const int idx = blockIdx.x * blockDim.x + threadIdx.x;
  if (idx < K * EMBD) {
    const int k = idx >> 7, n = idx & 127;
    Wt[(size_t)n * K + k] = f2bf(W[(size_t)k * EMBD + n]);
  }
}

// ---------------- MFMA GEMM core ----------------
// block: 32 rows x 128 cols, 256 thr = 4 waves; wave w -> cols [w*32, w*32+32)
// A in LDS: [32][SA] bf16 (SA padded). B = W^T [128][KTOT] bf16 in global,
// staged per 32-k chunk into Wb [128][40].
// frag maps (16x16x32): A: m=lane&15, k=kc+(lane>>4)*8+j ; B: n=lane&15 (slice),
// k likewise ; D reg r: row=(lane>>4)*4+r, col=lane&15.

template <int KTOT, int SA>
__device__ __forceinline__ void do_gemm(const unsigned short* Ab, unsigned short* Wb,
                                        const unsigned short* __restrict__ Wt,
                                        const int t, const int m, const int kg,
                                        const int w, f32x4 acc[2][2]) {
#pragma unroll 1
  for (int kc = 0; kc < KTOT; kc += 32) {
    __syncthreads();
    {
      const int n0 = t >> 2, p0 = t & 3;
      *(uint4*)&Wb[n0 * 40 + p0 * 8] = *(const uint4*)&Wt[(size_t)n0 * KTOT + kc + p0 * 8];
      const int n1 = n0 + 64;
      *(uint4*)&Wb[n1 * 40 + p0 * 8] = *(const uint4*)&Wt[(size_t)n1 * KTOT + kc + p0 * 8];
    }
    __syncthreads();
    const bf16x8 a0 = *(const bf16x8*)&Ab[m * SA + kc + kg * 8];
    const bf16x8 a1 = *(const bf16x8*)&Ab[(16 + m) * SA + kc + kg * 8];
    const bf16x8 b0 = *(const bf16x8*)&Wb[(w * 32 + m) * 40 + kg * 8];
    const bf16x8 b1 = *(const bf16x8*)&Wb[(w * 32 + 16 + m) * 40 + kg * 8];
    acc[0][0] = MFMA16(a0, b0, acc[0][0]);
    acc[0][1] = MFMA16(a0, b1, acc[0][1]);
    acc[1][0] = MFMA16(a1, b0, acc[1][0]);
    acc[1][1] = MFMA16(a1, b1, acc[1][1]);
  }
}

__device__ __forceinline__ void stats_epi(const f32x4 acc[2][2], float* red,
                                          float* __restrict__ statg, const int t,
                                          const int m, const int kg, const int w) {
#pragma unroll
  for (int nt = 0; nt < 2; ++nt) {
    float s = 0.f, q = 0.f;
#pragma unroll
    for (int mt = 0; mt < 2; ++mt)
#pragma unroll
      for (int r = 0; r < 4; ++r) {
        const float v = acc[mt][nt][r];
        s += v;
        q += v * v;
      }
    s += __shfl_xor(s, 16); s += __shfl_xor(s, 32);
    q += __shfl_xor(q, 16); q += __shfl_xor(q, 32);
    if (kg == 0) {
      const int c = w * 32 + nt * 16 + m;
      red[c] = s;
      red[128 + c] = q;
    }
  }
  __syncthreads();
  if (t < 128) {
    atomicAdd(&statg[t], red[t]);
    atomicAdd(&statg[128 + t], red[128 + t]);
  }
}

// ---------------- edge pipeline ----------------
// stat: [0,128) sum1 [128,256) sumsq1 [256,384) sc1 [384,512) sh1
//       [512,640) sum2 [640,768) sumsq2 [768,896) sc2 [896,1024) sh2

#define SAE 296  // A stride (288 + 8 pad), bf16 elems

template <int PASS>
__global__ __launch_bounds__(256) void k_edge(
    const unsigned short* __restrict__ xb, const int* __restrict__ idx_i,
    const int* __restrict__ idx_j, const float* __restrict__ ea,
    const unsigned short* __restrict__ W1t, const unsigned short* __restrict__ W2t,
    float* __restrict__ stat, const int* __restrict__ lst,
    const int* __restrict__ own, const float* __restrict__ dinv,
    float* __restrict__ agg) {
  __shared__ __align__(16) unsigned short Ab[32 * SAE];
  __shared__ __align__(16) unsigned short Wb[128 * 40];
  __shared__ float red[256];
  __shared__ int ownsh[32];
  __shared__ float dish[32];
  const int t = threadIdx.x;
  const int s0 = blockIdx.x * 32;
  // stage A = [xi | xj | ea] as bf16, 8 threads per row
  {
    const int r = t >> 3, sub = t & 7;
    const int e = (PASS == 2) ? lst[s0 + r] : (s0 + r);
    const int i = idx_i[e], j = idx_j[e];
    const uint4* xi = (const uint4*)(xb + (size_t)i * EMBD);
    const uint4* xj = (const uint4*)(xb + (size_t)j * EMBD);
    unsigned short* row = &Ab[r * SAE];
#pragma unroll
    for (int q = 0; q < 4; ++q) {
      const int c = sub + q * 8;  // 16B chunk id, [0,32)
      const uint4 v = (c < 16) ? xi[c] : xj[c - 16];
      *(uint4*)&row[c * 8] = v;
    }
    const float4 ev = *(const float4*)&ea[(size_t)e * 32 + sub * 4];
    short4 eb;
    eb.x = (short)f2bf(ev.x); eb.y = (short)f2bf(ev.y);
    eb.z = (short)f2bf(ev.z); eb.w = (short)f2bf(ev.w);
    *(short4*)&row[256 + sub * 4] = eb;
  }
  if (PASS == 2 && t < 32) {
    const int n = own[s0 + t];
    ownsh[t] = n;
    dish[t] = dinv[n];
  }
  const int lane = t & 63, w = t >> 6, m = lane & 15, kg = lane >> 4;
  const f32x4 zz = {0.f, 0.f, 0.f, 0.f};
  f32x4 acc[2][2] = {{zz, zz}, {zz, zz}};
  do_gemm<KIN, SAE>(Ab, Wb, W1t, t, m, kg, w, acc);
  if (PASS == 0) {
    stats_epi(acc, red, stat, t, m, kg, w);
    return;
  }
  // BN1 + ReLU in regs -> H1 bf16 back to Ab
  __syncthreads();  // all waves done reading A
#pragma unroll
  for (int nt = 0; nt < 2; ++nt) {
    const int c = w * 32 + nt * 16 + m;
    const float sc = stat[256 + c], sh = stat[384 + c];
#pragma unroll
    for (int mt = 0; mt < 2; ++mt)
#pragma unroll
      for (int r = 0; r < 4; ++r) {
        const int row = mt * 16 + kg * 4 + r;
        const float v = fmaxf(fmaf(acc[mt][nt][r], sc, sh), 0.f);
        Ab[row * SAE + c] = f2bf(v);
      }
  }
  f32x4 acc2[2][2] = {{zz, zz}, {zz, zz}};
  do_gemm<EMBD, SAE>(Ab, Wb, W2t, t, m, kg, w, acc2);  // first barrier covers H1 stores
  if (PASS == 1) {
    stats_epi(acc2, red, stat + 512, t, m, kg, w);
    return;
  }
  // PASS 2: BN2+ReLU, * dinv -> Hf (f32, reuse Ab), segmented sum into agg
  __syncthreads();
  float* Hf = (float*)Ab;  // [32][132]
#pragma unroll
  for (int nt = 0; nt < 2; ++nt) {
    const int c = w * 32 + nt * 16 + m;
    const float sc = stat[768 + c], sh = stat[896 + c];
#pragma unroll
    for (int mt = 0; mt < 2; ++mt)
#pragma unroll
      for (int r = 0; r < 4; ++r) {
        const int row = mt * 16 + kg * 4 + r;
        Hf[row * 132 + c] = fmaxf(fmaf(acc2[mt][nt][r], sc, sh), 0.f) * dish[row];
      }
  }
  __syncthreads();
  const int col = t & 127;
  const int r0 = (t >> 7) * 16;
  int cur = ownsh[r0];
  float run = 0.f;
#pragma unroll 1
  for (int rr = r0; rr < r0 + 16; ++rr) {
    const int o = ownsh[rr];
    if (o != cur) {
      atomicAdd(&agg[(size_t)cur * EMBD + col], run);
      run = 0.f;
      cur = o;
    }
    run += Hf[rr * 132 + col];
  }
  atomicAdd(&agg[(size_t)cur * EMBD + col], run);
}

// ---------------- node update GEMM ----------------
// Z = (nodes + agg) @ fW -> agg in place, stats -> stat[0..)

__global__ __launch_bounds__(256) void k_node(
    const float* __restrict__ nd, float* __restrict__ ag,
    const unsigned short* __restrict__ Wt, float* __restrict__ stat) {
  __shared__ __align__(16) unsigned short Ab[32 * 136];
  __shared__ __align__(16) unsigned short Wb[128 * 40];
  __shared__ float red[256];
  const int t = threadIdx.x;
  const int n0 = blockIdx.x * 32;
  {
    const int r = t >> 3, sub = t & 7;
    const int row = n0 + r;
    unsigned short* drow = &Ab[r * 136];
#pragma unroll
    for (int q = 0; q < 4; ++q) {
      const int f4 = sub + q * 8;
      float4 va;
      if (row < NN) {
        va = ((const float4*)(nd + (size_t)row * EMBD))[f4];
        const float4 vb = ((const float4*)(ag + (size_t)row * EMBD))[f4];
        va.x += vb.x; va.y += vb.y; va.z += vb.z; va.w += vb.w;
      } else {
        va.x = va.y = va.z = va.w = 0.f;
      }
      short4 b;
      b.x = (short)f2bf(va.x); b.y = (short)f2bf(va.y);
      b.z = (short)f2bf(va.z); b.w = (short)f2bf(va.w);
      *(short4*)&drow[f4 * 4] = b;
    }
  }
  const int lane = t & 63, w = t >> 6, m = lane & 15, kg = lane >> 4;
  const f32x4 zz = {0.f, 0.f, 0.f, 0.f};
  f32x4 acc[2][2] = {{zz, zz}, {zz, zz}};
  do_gemm<EMBD, 136>(Ab, Wb, Wt, t, m, kg, w, acc);
#pragma unroll
  for (int nt = 0; nt < 2; ++nt) {
    const int c = w * 32 + nt * 16 + m;
#pragma unroll
    for (int mt = 0; mt < 2; ++mt)
#pragma unroll
      for (int r = 0; r < 4; ++r) {
        const int row = n0 + mt * 16 + kg * 4 + r;
        if (row < NN) ag[(size_t)row * EMBD + c] = acc[mt][nt][r];
      }
  }
  stats_epi(acc, red, stat, t, m, kg, w);
}

// ---------------- BN finalize / node residual ----------------

__global__ void k_finalize(float* __restrict__ statbase, const float* __restrict__ g,
                           const float* __restrict__ be, float cnt) {
  const int t = threadIdx.x;
  if (t < EMBD) {
    const float s = statbase[t], sq = statbase[EMBD + t];
    const float m = s / cnt;
    float v = sq / cnt - m * m;
    v = fmaxf(v, 0.f);
    const float rs = rsqrtf(v + EPSV);
    const float sc = g[t] * rs;
    statbase[256 + t] = sc;
    statbase[384 + t] = be[t] - m * sc;
    statbase[t] = 0.f;
    statbase[EMBD + t] = 0.f;
  }
}

__global__ void k_update(float* __restrict__ nd, unsigned short* __restrict__ xb,
                         const float* __restrict__ Z, const float* __restrict__ stat) {
  const float* sc = stat + 256;
  const float* sh = stat + 384;
  const int total = NN * EMBD / 4;
  for (int i = blockIdx.x * blockDim.x + threadIdx.x; i < total;
       i += gridDim.x * blockDim.x) {
    const int c4 = i & 31;
    const float4 v = ((const float4*)Z)[i];
    const float4 s4 = ((const float4*)sc)[c4];
    const float4 h4 = ((const float4*)sh)[c4];
    float4 nv = ((float4*)nd)[i];
    nv.x += fmaxf(fmaf(v.x, s4.x, h4.x), 0.f);
    nv.y += fmaxf(fmaf(v.y, s4.y, h4.y), 0.f);
    nv.z += fmaxf(fmaf(v.z, s4.z, h4.z), 0.f);
    nv.w += fmaxf(fmaf(v.w, s4.w, h4.w), 0.f);
    ((float4*)nd)[i] = nv;
    short4 b;
    b.x = (short)f2bf(nv.x); b.y = (short)f2bf(nv.y);
    b.z = (short)f2bf(nv.z); b.w = (short)f2bf(nv.w);
    *(short4*)&xb[(size_t)i * 4] = b;
  }
}

// ---------------- launch ----------------

extern "C" void kernel_launch(void* const* d_in, const int* in_sizes, int n_in,
                              void* d_out, int out_size, void* d_ws, size_t ws_size,
                              hipStream_t stream) {
  const float* in_nodes = (const float*)d_in[0];
  const void* edges = d_in[1];
  const float* ea = (const float*)d_in[2];
  const float* fW = (const float*)d_in[3];
  const float* fg = (const float*)d_in[5];
  const float* fbe = (const float*)d_in[6];
  const float* p_[8];
  const float* c_[8];
  for (int i = 0; i < 8; ++i) {
    p_[i] = (const float*)d_in[7 + i];
    c_[i] = (const float*)d_in[15 + i];
  }
  float* nodes = (float*)d_out;

  char* base = (char*)d_ws;
  size_t cur = 0;
  auto take = [&](size_t bytes) -> void* {
    void* p = base + cur;
    cur = (cur + bytes + 255) & ~(size_t)255;
    return p;
  };
  float* agg = (float*)take((size_t)NN * EMBD * 4);            // 25.6 MB
  unsigned short* xb = (unsigned short*)take((size_t)NN * EMBD * 2);  // 12.8 MB
  int* src = (int*)take(EE * 4);
  int* dst = (int*)take(EE * 4);
  int* lstp = (int*)take(EE * 4);
  int* lstc = (int*)take(EE * 4);
  int* ownp = (int*)take(EE * 4);
  int* ownc = (int*)take(EE * 4);
  int* offp = (int*)take((NN + 1) * 4);
  int* offc = (int*)take((NN + 1) * 4);
  int* curp = (int*)take(NN * 4);
  int* curc = (int*)take(NN * 4);
  float* dinvp = (float*)take(NN * 4);
  float* dinvc = (float*)take(NN * 4);
  float* stat = (float*)take(1024 * 4);
  int* flag = (int*)take(4);
  unsigned short* pW1t = (unsigned short*)take((size_t)EMBD * KIN * 2);
  unsigned short* pW2t = (unsigned short*)take((size_t)EMBD * EMBD * 2);
  unsigned short* cW1t = (unsigned short*)take((size_t)EMBD * KIN * 2);
  unsigned short* cW2t = (unsigned short*)take((size_t)EMBD * EMBD * 2);
  unsigned short* fWt = (unsigned short*)take((size_t)EMBD * EMBD * 2);
  // total ~49.3 MB

  k_zeroi<<<64, 256, 0, stream>>>((int*)stat, 1024);
  k_zeroi<<<128, 256, 0, stream>>>(curp, NN);
  k_zeroi<<<128, 256, 0, stream>>>(curc, NN);
  k_detect<<<1, 256, 0, stream>>>((const long long*)edges, flag);
  k_convert<<<1024, 256, 0, stream>>>(edges, flag, src, dst);
  k_count<<<1024, 256, 0, stream>>>(src, dst, curp, curc);
  k_dinv<<<128, 256, 0, stream>>>(curp, curc, dinvp, dinvc);
  k_scan<<<2, 1024, 0, stream>>>(curp, curc, offp, offc);
  k_copycur<<<128, 256, 0, stream>>>(offp, offc, curp, curc);
  k_scatter<<<1024, 256, 0, stream>>>(src, dst, curp, curc, lstp, lstc, ownp, ownc);
  k_initnodes<<<2048, 256, 0, stream>>>(in_nodes, nodes, xb);
  k_prepW<<<(KIN * EMBD + 255) / 256, 256, 0, stream>>>(p_[0], pW1t, KIN);
  k_prepW<<<(EMBD * EMBD + 255) / 256, 256, 0, stream>>>(p_[4], pW2t, EMBD);
  k_prepW<<<(KIN * EMBD + 255) / 256, 256, 0, stream>>>(c_[0], cW1t, KIN);
  k_prepW<<<(EMBD * EMBD + 255) / 256, 256, 0, stream>>>(c_[4], cW2t, EMBD);
  k_prepW<<<(EMBD * EMBD + 255) / 256, 256, 0, stream>>>(fW, fWt, EMBD);

  const int EB = EE / 32;         // 12500
  const int NB = (NN + 31) / 32;  // 1563

  for (int it = 0; it < NITERS; ++it) {
    k_zerof4<<<2048, 256, 0, stream>>>(agg, NN * EMBD / 4);
    // parent phase: idx_i = dst, idx_j = src
    k_edge<0><<<EB, 256, 0, stream>>>(xb, dst, src, ea, pW1t, pW2t, stat,
                                      nullptr, nullptr, nullptr, nullptr);
    k_finalize<<<1, 128, 0, stream>>>(stat, p_[2], p_[3], (float)EE);
    k_edge<1><<<EB, 256, 0, stream>>>(xb, dst, src, ea, pW1t, pW2t, stat,
                                      nullptr, nullptr, nullptr, nullptr);
    k_finalize<<<1, 128, 0, stream>>>(stat + 512, p_[6], p_[7], (float)EE);
    k_edge<2><<<EB, 256, 0, stream>>>(xb, dst, src, ea, pW1t, pW2t, stat,
                                      lstp, ownp, dinvp, agg);
    // child phase: idx_i = src, idx_j = dst
    k_edge<0><<<EB, 256, 0, stream>>>(xb, src, dst, ea, cW1t, cW2t, stat,
                                      nullptr, nullptr, nullptr, nullptr);
    k_finalize<<<1, 128, 0, stream>>>(stat, c_[2], c_[3], (float)EE);
    k_edge<1><<<EB, 256, 0, stream>>>(xb, src, dst, ea, cW1t, cW2t, stat,
                                      nullptr, nullptr, nullptr, nullptr);
    k_finalize<<<1, 128, 0, stream>>>(stat + 512, c_[6], c_[7], (float)EE);
    k_edge<2><<<EB, 256, 0, stream>>>(xb, src, dst, ea, cW1t, cW2t, stat,
                                      lstc, ownc, dinvc, agg);
    // node update
    k_node<<<NB, 256, 0, stream>>>(nodes, agg, fWt, stat);
    k_finalize<<<1, 128, 0, stream>>>(stat, fg, fbe, (float)NN);
    k_update<<<2048, 256, 0, stream>>>(nodes, xb, agg, stat);
  }
}

// Round 4
// 1945.549 us; speedup vs baseline: 3.7953x; 1.7560x over previous
//
#include <hip/hip_runtime.h>
#include <math.h>

#define NN 50000
#define EE 400000
#define EMBD 128
#define KIN 288
#define NITERS 2
#define EPSV 1e-5f
#define SAE 296  // A LDS stride in bf16 elems (592B rows, 16B aligned, 2-way banks)

typedef __attribute__((ext_vector_type(8))) short bf16x8;
typedef __attribute__((ext_vector_type(4))) float f32x4;

#define MFMA16(a, b, c) __builtin_amdgcn_mfma_f32_16x16x32_bf16(a, b, c, 0, 0, 0)

__device__ __forceinline__ unsigned short f2bf(float x) {
  unsigned int u = __float_as_uint(x);
  u += 0x7fffu + ((u >> 16) & 1u);
  return (unsigned short)(u >> 16);
}

// swizzled 16B-chunk index for the H1 region (cols 0..127 => chunks 0..15)
__device__ __forceinline__ int physch(int ch, int row) {
  return (ch & 8) | ((ch ^ (row & 7)) & 7);
}
__device__ __forceinline__ int h1a(int row, int col) {
  return row * SAE + physch(col >> 3, row) * 8 + (col & 7);
}

// ---------------- zero / setup kernels ----------------

__global__ void k_zeroi(int* __restrict__ p, int n) {
  for (int i = blockIdx.x * blockDim.x + threadIdx.x; i < n;
       i += gridDim.x * blockDim.x)
    p[i] = 0;
}

__global__ void k_zerof4(float* __restrict__ p, int n4) {
  float4 z; z.x = z.y = z.z = z.w = 0.f;
  for (int i = blockIdx.x * blockDim.x + threadIdx.x; i < n4;
       i += gridDim.x * blockDim.x)
    ((float4*)p)[i] = z;
}

__global__ void k_detect(const long long* __restrict__ e64, int* __restrict__ flag) {
  __shared__ int ok;
  if (threadIdx.x == 0) ok = 1;
  __syncthreads();
  for (int i = threadIdx.x; i < 4096; i += blockDim.x) {
    const long long v = e64[i];
    if (v < 0 || v >= NN) atomicAnd(&ok, 0);
  }
  __syncthreads();
  if (threadIdx.x == 0) *flag = ok;
}

__global__ void k_convert(const void* __restrict__ edges, const int* __restrict__ flag,
                          int* __restrict__ src, int* __restrict__ dst) {
  const int is64 = *flag;
  for (int i = blockIdx.x * blockDim.x + threadIdx.x; i < 2 * EE;
       i += gridDim.x * blockDim.x) {
    const int v = is64 ? (int)((const long long*)edges)[i] : ((const int*)edges)[i];
    if (i < EE) src[i] = v; else dst[i - EE] = v;
  }
}

__global__ void k_count(const int* __restrict__ src, const int* __restrict__ dst,
                        int* __restrict__ degp, int* __restrict__ degc) {
  for (int e = blockIdx.x * blockDim.x + threadIdx.x; e < EE;
       e += gridDim.x * blockDim.x) {
    atomicAdd(&degp[dst[e]], 1);
    atomicAdd(&degc[src[e]], 1);
  }
}

__global__ void k_dinv(const int* __restrict__ dp, const int* __restrict__ dc,
                       float* __restrict__ ip, float* __restrict__ ic) {
  for (int n = blockIdx.x * blockDim.x + threadIdx.x; n < NN;
       n += gridDim.x * blockDim.x) {
    ip[n] = dp[n] ? 1.f / (float)dp[n] : 0.f;
    ic[n] = dc[n] ? 1.f / (float)dc[n] : 0.f;
  }
}

__global__ __launch_bounds__(1024) void k_scan(
    const int* __restrict__ degp, const int* __restrict__ degc,
    int* __restrict__ offp, int* __restrict__ offc) {
  const int* deg = blockIdx.x ? degc : degp;
  int* off = blockIdx.x ? offc : offp;
  __shared__ int sh[1024];
  const int t = threadIdx.x;
  int running = 0;
  for (int base = 0; base < NN; base += 1024) {
    const int v = (base + t < NN) ? deg[base + t] : 0;
    sh[t] = v;
    __syncthreads();
    for (int o = 1; o < 1024; o <<= 1) {
      const int y = (t >= o) ? sh[t - o] : 0;
      __syncthreads();
      sh[t] += y;
      __syncthreads();
    }
    if (base + t < NN) off[base + t] = running + sh[t] - v;
    running += sh[1023];
    __syncthreads();
  }
  if (t == 0) off[NN] = running;
}

__global__ void k_copycur(const int* __restrict__ offp, const int* __restrict__ offc,
                          int* __restrict__ curp, int* __restrict__ curc) {
  for (int i = blockIdx.x * blockDim.x + threadIdx.x; i < NN;
       i += gridDim.x * blockDim.x) {
    curp[i] = offp[i];
    curc[i] = offc[i];
  }
}

__global__ void k_scatter(const int* __restrict__ src, const int* __restrict__ dst,
                          int* __restrict__ curp, int* __restrict__ curc,
                          int* __restrict__ lstp, int* __restrict__ lstc,
                          int* __restrict__ ownp, int* __restrict__ ownc) {
  for (int e = blockIdx.x * blockDim.x + threadIdx.x; e < EE;
       e += gridDim.x * blockDim.x) {
    const int dp = dst[e];
    const int pp = atomicAdd(&curp[dp], 1);
    lstp[pp] = e;
    ownp[pp] = dp;
    const int sc = src[e];
    const int pc = atomicAdd(&curc[sc], 1);
    lstc[pc] = e;
    ownc[pc] = sc;
  }
}

__global__ void k_initnodes(const float* __restrict__ in, float* __restrict__ nd,
                            unsigned short* __restrict__ xb) {
  const int tot = NN * EMBD / 4;
  for (int i = blockIdx.x * blockDim.x + threadIdx.x; i < tot;
       i += gridDim.x * blockDim.x) {
    const float4 v = ((const float4*)in)[i];
    ((float4*)nd)[i] = v;
    short4 b;
    b.x = (short)f2bf(v.x); b.y = (short)f2bf(v.y);
    b.z = (short)f2bf(v.z); b.w = (short)f2bf(v.w);
    *(short4*)&xb[(size_t)i * 4] = b;
  }
}

// W [K][128] f32 -> Wt [128][K] bf16
__global__ void k_prepW(const float* __restrict__ W, unsigned short* __restrict__ Wt,
                        int K) {
  const int idx = blockIdx.x * blockDim.x + threadIdx.x;
  if (idx < K * EMBD) {
    const int k = idx >> 7, n = idx & 127;
    Wt[(size_t)n * K + k] = f2bf(W[(size_t)k * EMBD + n]);
  }
}

// ---------------- MFMA GEMM core (B from global, no barriers) ----------------
// block: 64 rows x 128 cols, 4 waves; wave w -> cols [w*32, w*32+32)
// acc[mt][nt]: rows mt*16.., cols w*32+nt*16..
// D frag: row = mt*16 + (lane>>4)*4 + r, col = w*32+nt*16 + (lane&15)

template <int NK, bool SWZ>
__device__ __forceinline__ void gemm_g(const unsigned short* Ab, const int sa,
                                       const unsigned short* __restrict__ Wt,
                                       const int K, const int m, const int kg,
                                       const int w, f32x4 acc[4][2]) {
  const int n0 = w * 32 + m, n1 = n0 + 16;
#pragma unroll
  for (int ks = 0; ks < NK; ++ks) {
    const int koff = ks * 32 + kg * 8;
    const int aoff = SWZ ? physch(koff >> 3, m) * 8 : koff;
    const bf16x8 b0 = *(const bf16x8*)&Wt[(size_t)n0 * K + koff];
    const bf16x8 b1 = *(const bf16x8*)&Wt[(size_t)n1 * K + koff];
#pragma unroll
    for (int mt = 0; mt < 4; ++mt) {
      const bf16x8 a = *(const bf16x8*)&Ab[(mt * 16 + m) * sa + aoff];
      acc[mt][0] = MFMA16(a, b0, acc[mt][0]);
      acc[mt][1] = MFMA16(a, b1, acc[mt][1]);
    }
  }
}

__device__ __forceinline__ void stats_epi64(const f32x4 acc[4][2], float* red,
                                            float* __restrict__ statg, const int t,
                                            const int m, const int kg, const int w) {
#pragma unroll
  for (int nt = 0; nt < 2; ++nt) {
    float s = 0.f, q = 0.f;
#pragma unroll
    for (int mt = 0; mt < 4; ++mt)
#pragma unroll
      for (int r = 0; r < 4; ++r) {
        const float v = acc[mt][nt][r];
        s += v;
        q += v * v;
      }
    s += __shfl_xor(s, 16); s += __shfl_xor(s, 32);
    q += __shfl_xor(q, 16); q += __shfl_xor(q, 32);
    if (kg == 0) {
      const int c = w * 32 + nt * 16 + m;
      red[c] = s;
      red[128 + c] = q;
    }
  }
  __syncthreads();
  if (t < 128) {
    atomicAdd(&statg[t], red[t]);
    atomicAdd(&statg[128 + t], red[128 + t]);
  }
}

// ---------------- edge pipeline ----------------
// stat: [0,128) sum1 [128,256) sumsq1 [256,384) sc1 [384,512) sh1
//       [512,640) sum2 [640,768) sumsq2 [768,896) sc2 [896,1024) sh2
// USEY1: PASS0 stores pre-BN Y1 (bf16); PASS1/2 read Y1 (no GEMM1, no gather).

template <int PASS, int USEY1>
__global__ __launch_bounds__(256) void k_edge(
    const unsigned short* __restrict__ xb, const int* __restrict__ idx_i,
    const int* __restrict__ idx_j, const float* __restrict__ ea,
    const unsigned short* __restrict__ W1t, const unsigned short* __restrict__ W2t,
    float* __restrict__ stat, const int* __restrict__ lst,
    const int* __restrict__ own, const float* __restrict__ dinv,
    float* __restrict__ agg, unsigned short* __restrict__ Y1) {
  __shared__ __align__(16) unsigned short Ab[64 * SAE];
  __shared__ float red[256];
  __shared__ float scsh[256];
  __shared__ int ownsh[64];
  __shared__ float dish[64];
  const int t = threadIdx.x;
  const int s0 = blockIdx.x * 64;
  const int lane = t & 63, w = t >> 6, m = lane & 15, kg = lane >> 4;

  if (PASS == 2 && t < 64) {
    const int n = own[s0 + t];
    ownsh[t] = n;
    dish[t] = dinv[n];
  }

  if (USEY1 && PASS >= 1) {
    scsh[t] = stat[256 + t];  // [0,128)=sc1 [128,256)=sh1
    __syncthreads();
    const int r = t >> 2, sub = t & 3;
    const int e = (PASS == 2) ? lst[s0 + r] : (s0 + r);
    const unsigned short* yrow = Y1 + (size_t)e * EMBD;
#pragma unroll
    for (int q = 0; q < 4; ++q) {
      const int ch = sub + q * 4;
      const uint4 v = *(const uint4*)&yrow[ch * 8];
      const unsigned int* pv = (const unsigned int*)&v;
      union { unsigned short s[8]; uint4 v4; } out;
#pragma unroll
      for (int h = 0; h < 4; ++h) {
        const unsigned int pw = pv[h];
        const float f0 = __uint_as_float(pw << 16);
        const float f1 = __uint_as_float(pw & 0xffff0000u);
        const int c0 = ch * 8 + h * 2;
        out.s[h * 2] = f2bf(fmaxf(fmaf(f0, scsh[c0], scsh[128 + c0]), 0.f));
        out.s[h * 2 + 1] = f2bf(fmaxf(fmaf(f1, scsh[c0 + 1], scsh[129 + c0]), 0.f));
      }
      *(uint4*)&Ab[r * SAE + physch(ch, r) * 8] = out.v4;
    }
    __syncthreads();
  } else {
    // stage A = [xi | xj | ea] bf16, linear layout, 4 threads per row
    const int r = t >> 2, sub = t & 3;
    const int e = (PASS == 2) ? lst[s0 + r] : (s0 + r);
    const int i = idx_i[e], j = idx_j[e];
    const uint4* xi = (const uint4*)(xb + (size_t)i * EMBD);
    const uint4* xj = (const uint4*)(xb + (size_t)j * EMBD);
#pragma unroll
    for (int q = 0; q < 9; ++q) {
      const int c = sub + q * 4;  // 16B chunk, [0,36)
      uint4 v;
      if (c < 16) v = xi[c];
      else if (c < 32) v = xj[c - 16];
      else {
        const float4 e0 = *(const float4*)&ea[(size_t)e * 32 + (c - 32) * 8];
        const float4 e1 = *(const float4*)&ea[(size_t)e * 32 + (c - 32) * 8 + 4];
        union { unsigned short s[8]; uint4 v4; } o;
        o.s[0] = f2bf(e0.x); o.s[1] = f2bf(e0.y); o.s[2] = f2bf(e0.z);
        o.s[3] = f2bf(e0.w); o.s[4] = f2bf(e1.x); o.s[5] = f2bf(e1.y);
        o.s[6] = f2bf(e1.z); o.s[7] = f2bf(e1.w);
        v = o.v4;
      }
      *(uint4*)&Ab[r * SAE + c * 8] = v;
    }
    __syncthreads();
  }

  const f32x4 zz = {0.f, 0.f, 0.f, 0.f};
  if (!(USEY1 && PASS >= 1)) {
    f32x4 acc[4][2] = {{zz, zz}, {zz, zz}, {zz, zz}, {zz, zz}};
    gemm_g<9, false>(Ab, SAE, W1t, KIN, m, kg, w, acc);
    if (PASS == 0) {
      stats_epi64(acc, red, stat, t, m, kg, w);
      if (USEY1) {
        // raw pre-BN Y1 -> LDS (swizzled) -> global, coalesced rows
#pragma unroll
        for (int nt = 0; nt < 2; ++nt) {
          const int c = w * 32 + nt * 16 + m;
#pragma unroll
          for (int mt = 0; mt < 4; ++mt)
#pragma unroll
            for (int r2 = 0; r2 < 4; ++r2)
              Ab[h1a(mt * 16 + kg * 4 + r2, c)] = f2bf(acc[mt][nt][r2]);
        }
        __syncthreads();
        const int rr = t >> 2, sub = t & 3;
        unsigned short* yrow = Y1 + (size_t)(s0 + rr) * EMBD;
#pragma unroll
        for (int q = 0; q < 4; ++q) {
          const int ch = sub + q * 4;
          *(uint4*)&yrow[ch * 8] = *(const uint4*)&Ab[rr * SAE + physch(ch, rr) * 8];
        }
      }
      return;
    }
    // fallback PASS>=1: BN1+ReLU -> H1 (swizzled bf16) back into Ab
    __syncthreads();  // all waves done reading A
#pragma unroll
    for (int nt = 0; nt < 2; ++nt) {
      const int c = w * 32 + nt * 16 + m;
      const float sc = stat[256 + c], sh = stat[384 + c];
#pragma unroll
      for (int mt = 0; mt < 4; ++mt)
#pragma unroll
        for (int r2 = 0; r2 < 4; ++r2) {
          const float v = fmaxf(fmaf(acc[mt][nt][r2], sc, sh), 0.f);
          Ab[h1a(mt * 16 + kg * 4 + r2, c)] = f2bf(v);
        }
    }
    __syncthreads();
  }

  f32x4 acc2[4][2] = {{zz, zz}, {zz, zz}, {zz, zz}, {zz, zz}};
  gemm_g<4, true>(Ab, SAE, W2t, EMBD, m, kg, w, acc2);
  if (PASS == 1) {
    stats_epi64(acc2, red, stat + 512, t, m, kg, w);
    return;
  }
  // PASS 2: BN2+ReLU, * dinv -> Hf (f32), segmented sum into agg
  __syncthreads();
  float* Hf = (float*)Ab;  // [64][132]
#pragma unroll
  for (int nt = 0; nt < 2; ++nt) {
    const int c = w * 32 + nt * 16 + m;
    const float sc = stat[768 + c], sh = stat[896 + c];
#pragma unroll
    for (int mt = 0; mt < 4; ++mt)
#pragma unroll
      for (int r2 = 0; r2 < 4; ++r2) {
        const int row = mt * 16 + kg * 4 + r2;
        Hf[row * 132 + c] = fmaxf(fmaf(acc2[mt][nt][r2], sc, sh), 0.f) * dish[row];
      }
  }
  __syncthreads();
  const int col = t & 127;
  const int r0 = (t >> 7) * 32;
  int curo = ownsh[r0];
  float run = 0.f;
#pragma unroll 1
  for (int rr = r0; rr < r0 + 32; ++rr) {
    const int o = ownsh[rr];
    if (o != curo) {
      atomicAdd(&agg[(size_t)curo * EMBD + col], run);
      run = 0.f;
      curo = o;
    }
    run += Hf[rr * 132 + col];
  }
  atomicAdd(&agg[(size_t)curo * EMBD + col], run);
}

// ---------------- node update GEMM ----------------
// Z = (nodes + agg) @ fW -> agg in place (64-row blocks), stats -> stat[0..)

__global__ __launch_bounds__(256) void k_node(
    const float* __restrict__ nd, float* __restrict__ ag,
    const unsigned short* __restrict__ Wt, float* __restrict__ stat) {
  __shared__ __align__(16) unsigned short Ab[64 * 136];
  __shared__ float red[256];
  const int t = threadIdx.x;
  const int n0 = blockIdx.x * 64;
  {
    const int r = t >> 2, sub = t & 3;
    const int row = n0 + r;
    unsigned short* drow = &Ab[r * 136];
#pragma unroll
    for (int q = 0; q < 8; ++q) {
      const int c4 = sub + q * 4;  // float4 chunk, [0,32)
      float4 va;
      if (row < NN) {
        va = ((const float4*)(nd + (size_t)row * EMBD))[c4];
        const float4 vb = ((const float4*)(ag + (size_t)row * EMBD))[c4];
        va.x += vb.x; va.y += vb.y; va.z += vb.z; va.w += vb.w;
      } else {
        va.x = va.y = va.z = va.w = 0.f;
      }
      short4 b;
      b.x = (short)f2bf(va.x); b.y = (short)f2bf(va.y);
      b.z = (short)f2bf(va.z); b.w = (short)f2bf(va.w);
      *(short4*)&drow[c4 * 4] = b;
    }
  }
  __syncthreads();
  const int lane = t & 63, w = t >> 6, m = lane & 15, kg = lane >> 4;
  const f32x4 zz = {0.f, 0.f, 0.f, 0.f};
  f32x4 acc[4][2] = {{zz, zz}, {zz, zz}, {zz, zz}, {zz, zz}};
  gemm_g<4, false>(Ab, 136, Wt, EMBD, m, kg, w, acc);
#pragma unroll
  for (int nt = 0; nt < 2; ++nt) {
    const int c = w * 32 + nt * 16 + m;
#pragma unroll
    for (int mt = 0; mt < 4; ++mt)
#pragma unroll
      for (int r = 0; r < 4; ++r) {
        const int row = n0 + mt * 16 + kg * 4 + r;
        if (row < NN) ag[(size_t)row * EMBD + c] = acc[mt][nt][r];
      }
  }
  stats_epi64(acc, red, stat, t, m, kg, w);
}

// ---------------- BN finalize / node residual ----------------

__global__ void k_finalize(float* __restrict__ statbase, const float* __restrict__ g,
                           const float* __restrict__ be, float cnt) {
  const int t = threadIdx.x;
  if (t < EMBD) {
    const float s = statbase[t], sq = statbase[EMBD + t];
    const float m = s / cnt;
    float v = sq / cnt - m * m;
    v = fmaxf(v, 0.f);
    const float rs = rsqrtf(v + EPSV);
    const float sc = g[t] * rs;
    statbase[256 + t] = sc;
    statbase[384 + t] = be[t] - m * sc;
    statbase[t] = 0.f;
    statbase[EMBD + t] = 0.f;
  }
}

__global__ void k_update(float* __restrict__ nd, unsigned short* __restrict__ xb,
                         const float* __restrict__ Z, const float* __restrict__ stat) {
  const float* sc = stat + 256;
  const float* sh = stat + 384;
  const int total = NN * EMBD / 4;
  for (int i = blockIdx.x * blockDim.x + threadIdx.x; i < total;
       i += gridDim.x * blockDim.x) {
    const int c4 = i & 31;
    const float4 v = ((const float4*)Z)[i];
    const float4 s4 = ((const float4*)sc)[c4];
    const float4 h4 = ((const float4*)sh)[c4];
    float4 nv = ((float4*)nd)[i];
    nv.x += fmaxf(fmaf(v.x, s4.x, h4.x), 0.f);
    nv.y += fmaxf(fmaf(v.y, s4.y, h4.y), 0.f);
    nv.z += fmaxf(fmaf(v.z, s4.z, h4.z), 0.f);
    nv.w += fmaxf(fmaf(v.w, s4.w, h4.w), 0.f);
    ((float4*)nd)[i] = nv;
    short4 b;
    b.x = (short)f2bf(nv.x); b.y = (short)f2bf(nv.y);
    b.z = (short)f2bf(nv.z); b.w = (short)f2bf(nv.w);
    *(short4*)&xb[(size_t)i * 4] = b;
  }
}

// ---------------- launch ----------------

extern "C" void kernel_launch(void* const* d_in, const int* in_sizes, int n_in,
                              void* d_out, int out_size, void* d_ws, size_t ws_size,
                              hipStream_t stream) {
  const float* in_nodes = (const float*)d_in[0];
  const void* edges = d_in[1];
  const float* ea = (const float*)d_in[2];
  const float* fW = (const float*)d_in[3];
  const float* fg = (const float*)d_in[5];
  const float* fbe = (const float*)d_in[6];
  const float* p_[8];
  const float* c_[8];
  for (int i = 0; i < 8; ++i) {
    p_[i] = (const float*)d_in[7 + i];
    c_[i] = (const float*)d_in[15 + i];
  }
  float* nodes = (float*)d_out;

  char* base = (char*)d_ws;
  size_t cur = 0;
  auto take = [&](size_t bytes) -> void* {
    void* p = base + cur;
    cur = (cur + bytes + 255) & ~(size_t)255;
    return p;
  };
  float* agg = (float*)take((size_t)NN * EMBD * 4);
  unsigned short* xb = (unsigned short*)take((size_t)NN * EMBD * 2);
  int* src = (int*)take(EE * 4);
  int* dst = (int*)take(EE * 4);
  int* lstp = (int*)take(EE * 4);
  int* lstc = (int*)take(EE * 4);
  int* ownp = (int*)take(EE * 4);
  int* ownc = (int*)take(EE * 4);
  int* offp = (int*)take((NN + 1) * 4);
  int* offc = (int*)take((NN + 1) * 4);
  int* curp = (int*)take(NN * 4);
  int* curc = (int*)take(NN * 4);
  float* dinvp = (float*)take(NN * 4);
  float* dinvc = (float*)take(NN * 4);
  float* stat = (float*)take(1024 * 4);
  int* flag = (int*)take(4);
  unsigned short* pW1t = (unsigned short*)take((size_t)EMBD * KIN * 2);
  unsigned short* pW2t = (unsigned short*)take((size_t)EMBD * EMBD * 2);
  unsigned short* cW1t = (unsigned short*)take((size_t)EMBD * KIN * 2);
  unsigned short* cW2t = (unsigned short*)take((size_t)EMBD * EMBD * 2);
  unsigned short* fWt = (unsigned short*)take((size_t)EMBD * EMBD * 2);
  // ~49.4 MB so far. Y1 (102.4 MB) only if workspace allows:
  const size_t y1_bytes = (size_t)EE * EMBD * 2;
  const bool useY1 = (cur + y1_bytes) <= ws_size;
  unsigned short* Y1 = useY1 ? (unsigned short*)take(y1_bytes) : nullptr;

  k_zeroi<<<64, 256, 0, stream>>>((int*)stat, 1024);
  k_zeroi<<<128, 256, 0, stream>>>(curp, NN);
  k_zeroi<<<128, 256, 0, stream>>>(curc, NN);
  k_detect<<<1, 256, 0, stream>>>((const long long*)edges, flag);
  k_convert<<<1024, 256, 0, stream>>>(edges, flag, src, dst);
  k_count<<<1024, 256, 0, stream>>>(src, dst, curp, curc);
  k_dinv<<<128, 256, 0, stream>>>(curp, curc, dinvp, dinvc);
  k_scan<<<2, 1024, 0, stream>>>(curp, curc, offp, offc);
  k_copycur<<<128, 256, 0, stream>>>(offp, offc, curp, curc);
  k_scatter<<<1024, 256, 0, stream>>>(src, dst, curp, curc, lstp, lstc, ownp, ownc);
  k_initnodes<<<2048, 256, 0, stream>>>(in_nodes, nodes, xb);
  k_prepW<<<(KIN * EMBD + 255) / 256, 256, 0, stream>>>(p_[0], pW1t, KIN);
  k_prepW<<<(EMBD * EMBD + 255) / 256, 256, 0, stream>>>(p_[4], pW2t, EMBD);
  k_prepW<<<(KIN * EMBD + 255) / 256, 256, 0, stream>>>(c_[0], cW1t, KIN);
  k_prepW<<<(EMBD * EMBD + 255) / 256, 256, 0, stream>>>(c_[4], cW2t, EMBD);
  k_prepW<<<(EMBD * EMBD + 255) / 256, 256, 0, stream>>>(fW, fWt, EMBD);

  const int EB = EE / 64;         // 6250
  const int NB = (NN + 63) / 64;  // 782

  for (int it = 0; it < NITERS; ++it) {
    k_zerof4<<<2048, 256, 0, stream>>>(agg, NN * EMBD / 4);
    for (int ph = 0; ph < 2; ++ph) {
      const int* ii = ph ? src : dst;
      const int* jj = ph ? dst : src;
      const unsigned short* W1 = ph ? cW1t : pW1t;
      const unsigned short* W2 = ph ? cW2t : pW2t;
      const float* g1 = ph ? c_[2] : p_[2];
      const float* b1 = ph ? c_[3] : p_[3];
      const float* g2 = ph ? c_[6] : p_[6];
      const float* b2 = ph ? c_[7] : p_[7];
      const int* lst = ph ? lstc : lstp;
      const int* own = ph ? ownc : ownp;
      const float* dinv = ph ? dinvc : dinvp;
      if (useY1) {
        k_edge<0, 1><<<EB, 256, 0, stream>>>(xb, ii, jj, ea, W1, W2, stat,
                                             nullptr, nullptr, nullptr, nullptr, Y1);
        k_finalize<<<1, 128, 0, stream>>>(stat, g1, b1, (float)EE);
        k_edge<1, 1><<<EB, 256, 0, stream>>>(xb, ii, jj, ea, W1, W2, stat,
                                             nullptr, nullptr, nullptr, nullptr, Y1);
        k_finalize<<<1, 128, 0, stream>>>(stat + 512, g2, b2, (float)EE);
        k_edge<2, 1><<<EB, 256, 0, stream>>>(xb, ii, jj, ea, W1, W2, stat,
                                             lst, own, dinv, agg, Y1);
      } else {
        k_edge<0, 0><<<EB, 256, 0, stream>>>(xb, ii, jj, ea, W1, W2, stat,
                                             nullptr, nullptr, nullptr, nullptr, nullptr);
        k_finalize<<<1, 128, 0, stream>>>(stat, g1, b1, (float)EE);
        k_edge<1, 0><<<EB, 256, 0, stream>>>(xb, ii, jj, ea, W1, W2, stat,
                                             nullptr, nullptr, nullptr, nullptr, nullptr);
        k_finalize<<<1, 128, 0, stream>>>(stat + 512, g2, b2, (float)EE);
        k_edge<2, 0><<<EB, 256, 0, stream>>>(xb, ii, jj, ea, W1, W2, stat,
                                             lst, own, dinv, agg, nullptr);
      }
    }
    k_node<<<NB, 256, 0, stream>>>(nodes, agg, fWt, stat);
    k_finalize<<<1, 128, 0, stream>>>(stat, fg, fbe, (float)NN);
    k_update<<<2048, 256, 0, stream>>>(nodes, xb, agg, stat);
  }
}

// Round 5
// 1373.823 us; speedup vs baseline: 5.3747x; 1.4162x over previous
//
#include <hip/hip_runtime.h>
#include <math.h>

#define NN 50000
#define EE 400000
#define EMBD 128
#define KIN 288
#define NITERS 2
#define EPSV 1e-5f
#define SAE 296      // pass0 A LDS stride (bf16 elems)
#define SA1 136      // pass1/node A LDS stride
#define NT_E 6250    // EE/64
#define G0 512
#define G1 1024

typedef __attribute__((ext_vector_type(8))) short bf16x8;
typedef __attribute__((ext_vector_type(4))) float f32x4;

#define MFMA16(a, b, c) __builtin_amdgcn_mfma_f32_16x16x32_bf16(a, b, c, 0, 0, 0)

__device__ __forceinline__ unsigned short f2bf(float x) {
  unsigned int u = __float_as_uint(x);
  u += 0x7fffu + ((u >> 16) & 1u);
  return (unsigned short)(u >> 16);
}

// swizzled 16B-chunk index: XOR low3 with row&7 (x-region chunks <32 only)
__device__ __forceinline__ int physch(int ch, int row) {
  return (ch < 32) ? ((ch & ~7) | ((ch ^ (row & 7)) & 7)) : ch;
}

// ---------------- setup kernels ----------------

__global__ void k_zeroi(int* __restrict__ p, int n) {
  for (int i = blockIdx.x * blockDim.x + threadIdx.x; i < n;
       i += gridDim.x * blockDim.x)
    p[i] = 0;
}

__global__ void k_detect(const long long* __restrict__ e64, int* __restrict__ flag) {
  __shared__ int ok;
  if (threadIdx.x == 0) ok = 1;
  __syncthreads();
  for (int i = threadIdx.x; i < 4096; i += blockDim.x) {
    const long long v = e64[i];
    if (v < 0 || v >= NN) atomicAnd(&ok, 0);
  }
  __syncthreads();
  if (threadIdx.x == 0) *flag = ok;
}

__global__ void k_convert(const void* __restrict__ edges, const int* __restrict__ flag,
                          int* __restrict__ src, int* __restrict__ dst) {
  const int is64 = *flag;
  for (int i = blockIdx.x * blockDim.x + threadIdx.x; i < 2 * EE;
       i += gridDim.x * blockDim.x) {
    const int v = is64 ? (int)((const long long*)edges)[i] : ((const int*)edges)[i];
    if (i < EE) src[i] = v; else dst[i - EE] = v;
  }
}

__global__ void k_count(const int* __restrict__ src, const int* __restrict__ dst,
                        int* __restrict__ degp, int* __restrict__ degc) {
  for (int e = blockIdx.x * blockDim.x + threadIdx.x; e < EE;
       e += gridDim.x * blockDim.x) {
    atomicAdd(&degp[dst[e]], 1);
    atomicAdd(&degc[src[e]], 1);
  }
}

__global__ void k_dinv(const int* __restrict__ dp, const int* __restrict__ dc,
                       float* __restrict__ ip, float* __restrict__ ic) {
  for (int n = blockIdx.x * blockDim.x + threadIdx.x; n < NN;
       n += gridDim.x * blockDim.x) {
    ip[n] = dp[n] ? 1.f / (float)dp[n] : 0.f;
    ic[n] = dc[n] ? 1.f / (float)dc[n] : 0.f;
  }
}

__global__ __launch_bounds__(1024) void k_scan(
    const int* __restrict__ degp, const int* __restrict__ degc,
    int* __restrict__ offp, int* __restrict__ offc) {
  const int* deg = blockIdx.x ? degc : degp;
  int* off = blockIdx.x ? offc : offp;
  __shared__ int sh[1024];
  const int t = threadIdx.x;
  int running = 0;
  for (int base = 0; base < NN; base += 1024) {
    const int v = (base + t < NN) ? deg[base + t] : 0;
    sh[t] = v;
    __syncthreads();
    for (int o = 1; o < 1024; o <<= 1) {
      const int y = (t >= o) ? sh[t - o] : 0;
      __syncthreads();
      sh[t] += y;
      __syncthreads();
    }
    if (base + t < NN) off[base + t] = running + sh[t] - v;
    running += sh[1023];
    __syncthreads();
  }
  if (t == 0) off[NN] = running;
}

__global__ void k_copycur(const int* __restrict__ offp, const int* __restrict__ offc,
                          int* __restrict__ curp, int* __restrict__ curc) {
  for (int i = blockIdx.x * blockDim.x + threadIdx.x; i < NN;
       i += gridDim.x * blockDim.x) {
    curp[i] = offp[i];
    curc[i] = offc[i];
  }
}

__global__ void k_scatter(const int* __restrict__ src, const int* __restrict__ dst,
                          int* __restrict__ curp, int* __restrict__ curc,
                          int* __restrict__ lstp, int* __restrict__ lstc) {
  for (int e = blockIdx.x * blockDim.x + threadIdx.x; e < EE;
       e += gridDim.x * blockDim.x) {
    const int pp = atomicAdd(&curp[dst[e]], 1);
    lstp[pp] = e;
    const int pc = atomicAdd(&curc[src[e]], 1);
    lstc[pc] = e;
  }
}

__global__ void k_initnodes(const float* __restrict__ in, float* __restrict__ nd,
                            unsigned short* __restrict__ xb) {
  const int tot = NN * EMBD / 4;
  for (int i = blockIdx.x * blockDim.x + threadIdx.x; i < tot;
       i += gridDim.x * blockDim.x) {
    const float4 v = ((const float4*)in)[i];
    ((float4*)nd)[i] = v;
    short4 b;
    b.x = (short)f2bf(v.x); b.y = (short)f2bf(v.y);
    b.z = (short)f2bf(v.z); b.w = (short)f2bf(v.w);
    *(short4*)&xb[(size_t)i * 4] = b;
  }
}

// W [K][128] f32 -> Wt [128][K] bf16
__global__ void k_prepW(const float* __restrict__ W, unsigned short* __restrict__ Wt,
                        int K) {
  const int idx = blockIdx.x * blockDim.x + threadIdx.x;
  if (idx < K * EMBD) {
    const int k = idx >> 7, n = idx & 127;
    Wt[(size_t)n * K + k] = f2bf(W[(size_t)k * EMBD + n]);
  }
}

// ---------------- PASS0: GEMM1 -> stats1 + Y1 (pre-BN, bf16) ----------------
// persistent blocks, W1^T in registers, T14 staged gather.

__global__ __launch_bounds__(256, 2) void k_pass0(
    const unsigned short* __restrict__ xb, const int* __restrict__ idx_i,
    const int* __restrict__ idx_j, const float* __restrict__ ea,
    const unsigned short* __restrict__ W1t, float* __restrict__ stat,
    unsigned short* __restrict__ Y1) {
  __shared__ __align__(16) unsigned short Ab[64 * SAE];
  __shared__ float red[256];
  const int t = threadIdx.x;
  const int lane = t & 63, w = t >> 6, m = lane & 15, kg = lane >> 4;
  const int r = t >> 2, sub = t & 3;
  const int n0 = w * 32 + m, n1 = n0 + 16;
  bf16x8 B0[9], B1[9];
#pragma unroll
  for (int ks = 0; ks < 9; ++ks) {
    B0[ks] = *(const bf16x8*)&W1t[(size_t)n0 * KIN + ks * 32 + kg * 8];
    B1[ks] = *(const bf16x8*)&W1t[(size_t)n1 * KIN + ks * 32 + kg * 8];
  }
  float s0 = 0.f, s1 = 0.f, q0 = 0.f, q1 = 0.f;
  uint4 xreg[8];
  float eareg[8];
  int tile = blockIdx.x;
  {
    const int e = tile * 64 + r;
    const int i = idx_i[e], j = idx_j[e];
    const uint4* xi = (const uint4*)(xb + (size_t)i * EMBD);
    const uint4* xj = (const uint4*)(xb + (size_t)j * EMBD);
#pragma unroll
    for (int qq = 0; qq < 8; ++qq) {
      const int c = sub + qq * 4;
      xreg[qq] = (c < 16) ? xi[c] : xj[c - 16];
    }
    *(float4*)&eareg[0] = *(const float4*)&ea[(size_t)e * 32 + sub * 8];
    *(float4*)&eareg[4] = *(const float4*)&ea[(size_t)e * 32 + sub * 8 + 4];
  }
  while (tile < NT_E) {
    __syncthreads();  // Ab free
    unsigned short* rowp = &Ab[r * SAE];
#pragma unroll
    for (int qq = 0; qq < 8; ++qq) {
      const int c = sub + qq * 4;
      *(uint4*)&rowp[physch(c, r) * 8] = xreg[qq];
    }
    {
      union { unsigned short u[8]; uint4 v; } o;
#pragma unroll
      for (int h = 0; h < 8; ++h) o.u[h] = f2bf(eareg[h]);
      *(uint4*)&rowp[(32 + sub) * 8] = o.v;
    }
    __syncthreads();
    const int next = tile + gridDim.x;
    if (next < NT_E) {  // T14: issue next tile's gather, overlaps MFMAs below
      const int e = next * 64 + r;
      const int i = idx_i[e], j = idx_j[e];
      const uint4* xi = (const uint4*)(xb + (size_t)i * EMBD);
      const uint4* xj = (const uint4*)(xb + (size_t)j * EMBD);
#pragma unroll
      for (int qq = 0; qq < 8; ++qq) {
        const int c = sub + qq * 4;
        xreg[qq] = (c < 16) ? xi[c] : xj[c - 16];
      }
      *(float4*)&eareg[0] = *(const float4*)&ea[(size_t)e * 32 + sub * 8];
      *(float4*)&eareg[4] = *(const float4*)&ea[(size_t)e * 32 + sub * 8 + 4];
    }
    const f32x4 zz = {0.f, 0.f, 0.f, 0.f};
    f32x4 acc[4][2] = {{zz, zz}, {zz, zz}, {zz, zz}, {zz, zz}};
#pragma unroll
    for (int ks = 0; ks < 9; ++ks) {
      const int aoff = physch(ks * 4 + kg, m) * 8;
#pragma unroll
      for (int mt = 0; mt < 4; ++mt) {
        const bf16x8 a = *(const bf16x8*)&Ab[(mt * 16 + m) * SAE + aoff];
        acc[mt][0] = MFMA16(a, B0[ks], acc[mt][0]);
        acc[mt][1] = MFMA16(a, B1[ks], acc[mt][1]);
      }
    }
#pragma unroll
    for (int mt = 0; mt < 4; ++mt)
#pragma unroll
      for (int r2 = 0; r2 < 4; ++r2) {
        const float v0 = acc[mt][0][r2], v1 = acc[mt][1][r2];
        s0 += v0; q0 += v0 * v0;
        s1 += v1; q1 += v1 * v1;
      }
    __syncthreads();  // all waves done reading Ab
#pragma unroll
    for (int nt = 0; nt < 2; ++nt) {
      const int c = w * 32 + nt * 16 + m;
      const int cc = c >> 3, cl = c & 7;
#pragma unroll
      for (int mt = 0; mt < 4; ++mt)
#pragma unroll
        for (int r2 = 0; r2 < 4; ++r2) {
          const int rw = mt * 16 + kg * 4 + r2;
          Ab[rw * SAE + physch(cc, rw) * 8 + cl] = f2bf(acc[mt][nt][r2]);
        }
    }
    __syncthreads();
    unsigned short* yrow = Y1 + (size_t)(tile * 64 + r) * EMBD;
#pragma unroll
    for (int qq = 0; qq < 4; ++qq) {
      const int ch = sub + qq * 4;
      *(uint4*)&yrow[ch * 8] = *(const uint4*)&rowp[physch(ch, r) * 8];
    }
    tile = next;
  }
  s0 += __shfl_xor(s0, 16); s0 += __shfl_xor(s0, 32);
  q0 += __shfl_xor(q0, 16); q0 += __shfl_xor(q0, 32);
  s1 += __shfl_xor(s1, 16); s1 += __shfl_xor(s1, 32);
  q1 += __shfl_xor(q1, 16); q1 += __shfl_xor(q1, 32);
  if (kg == 0) {
    const int c0 = w * 32 + m, c1 = c0 + 16;
    red[c0] = s0; red[128 + c0] = q0;
    red[c1] = s1; red[128 + c1] = q1;
  }
  __syncthreads();
  if (t < 128) {
    atomicAdd(&stat[t], red[t]);
    atomicAdd(&stat[128 + t], red[128 + t]);
  }
}

// ---------------- PASS1: BN1+ReLU -> GEMM2 -> stats2 + Y2 over Y1 ----------------

__global__ __launch_bounds__(256, 4) void k_pass1(
    const unsigned short* __restrict__ W2t, float* __restrict__ stat,
    unsigned short* __restrict__ Y) {
  __shared__ __align__(16) unsigned short Ab[64 * SA1];
  __shared__ float red[256];
  __shared__ float scsh[256];
  const int t = threadIdx.x;
  const int lane = t & 63, w = t >> 6, m = lane & 15, kg = lane >> 4;
  const int r = t >> 2, sub = t & 3;
  const int n0 = w * 32 + m, n1 = n0 + 16;
  bf16x8 B0[4], B1[4];
#pragma unroll
  for (int ks = 0; ks < 4; ++ks) {
    B0[ks] = *(const bf16x8*)&W2t[(size_t)n0 * EMBD + ks * 32 + kg * 8];
    B1[ks] = *(const bf16x8*)&W2t[(size_t)n1 * EMBD + ks * 32 + kg * 8];
  }
  scsh[t] = stat[256 + t];  // [0,128)=sc1 [128,256)=sh1
  float s0 = 0.f, s1 = 0.f, q0 = 0.f, q1 = 0.f;
  uint4 yreg[4];
  int tile = blockIdx.x;
  {
    const unsigned short* yrow = Y + (size_t)(tile * 64 + r) * EMBD;
#pragma unroll
    for (int qq = 0; qq < 4; ++qq)
      yreg[qq] = *(const uint4*)&yrow[(sub + qq * 4) * 8];
  }
  while (tile < NT_E) {
    __syncthreads();  // scsh ready / Ab free
    unsigned short* rowp = &Ab[r * SA1];
#pragma unroll
    for (int qq = 0; qq < 4; ++qq) {
      const int ch = sub + qq * 4;
      const unsigned int* pv = (const unsigned int*)&yreg[qq];
      union { unsigned short u[8]; uint4 v; } o;
#pragma unroll
      for (int h = 0; h < 4; ++h) {
        const unsigned int pw = pv[h];
        const int c0 = ch * 8 + h * 2;
        const float f0 = __uint_as_float(pw << 16);
        const float f1 = __uint_as_float(pw & 0xffff0000u);
        o.u[h * 2] = f2bf(fmaxf(fmaf(f0, scsh[c0], scsh[128 + c0]), 0.f));
        o.u[h * 2 + 1] = f2bf(fmaxf(fmaf(f1, scsh[c0 + 1], scsh[129 + c0]), 0.f));
      }
      *(uint4*)&rowp[physch(ch, r) * 8] = o.v;
    }
    __syncthreads();
    const int next = tile + gridDim.x;
    if (next < NT_E) {
      const unsigned short* yrow = Y + (size_t)(next * 64 + r) * EMBD;
#pragma unroll
      for (int qq = 0; qq < 4; ++qq)
        yreg[qq] = *(const uint4*)&yrow[(sub + qq * 4) * 8];
    }
    const f32x4 zz = {0.f, 0.f, 0.f, 0.f};
    f32x4 acc[4][2] = {{zz, zz}, {zz, zz}, {zz, zz}, {zz, zz}};
#pragma unroll
    for (int ks = 0; ks < 4; ++ks) {
      const int aoff = physch(ks * 4 + kg, m) * 8;
#pragma unroll
      for (int mt = 0; mt < 4; ++mt) {
        const bf16x8 a = *(const bf16x8*)&Ab[(mt * 16 + m) * SA1 + aoff];
        acc[mt][0] = MFMA16(a, B0[ks], acc[mt][0]);
        acc[mt][1] = MFMA16(a, B1[ks], acc[mt][1]);
      }
    }
#pragma unroll
    for (int mt = 0; mt < 4; ++mt)
#pragma unroll
      for (int r2 = 0; r2 < 4; ++r2) {
        const float v0 = acc[mt][0][r2], v1 = acc[mt][1][r2];
        s0 += v0; q0 += v0 * v0;
        s1 += v1; q1 += v1 * v1;
      }
    __syncthreads();
#pragma unroll
    for (int nt = 0; nt < 2; ++nt) {
      const int c = w * 32 + nt * 16 + m;
      const int cc = c >> 3, cl = c & 7;
#pragma unroll
      for (int mt = 0; mt < 4; ++mt)
#pragma unroll
        for (int r2 = 0; r2 < 4; ++r2) {
          const int rw = mt * 16 + kg * 4 + r2;
          Ab[rw * SA1 + physch(cc, rw) * 8 + cl] = f2bf(acc[mt][nt][r2]);
        }
    }
    __syncthreads();
    unsigned short* yo = Y + (size_t)(tile * 64 + r) * EMBD;
#pragma unroll
    for (int qq = 0; qq < 4; ++qq) {
      const int ch = sub + qq * 4;
      *(uint4*)&yo[ch * 8] = *(const uint4*)&rowp[physch(ch, r) * 8];
    }
    tile = next;
  }
  s0 += __shfl_xor(s0, 16); s0 += __shfl_xor(s0, 32);
  q0 += __shfl_xor(q0, 16); q0 += __shfl_xor(q0, 32);
  s1 += __shfl_xor(s1, 16); s1 += __shfl_xor(s1, 32);
  q1 += __shfl_xor(q1, 16); q1 += __shfl_xor(q1, 32);
  if (kg == 0) {
    const int c0 = w * 32 + m, c1 = c0 + 16;
    red[c0] = s0; red[128 + c0] = q0;
    red[c1] = s1; red[128 + c1] = q1;
  }
  __syncthreads();
  if (t < 128) {
    atomicAdd(&stat[512 + t], red[t]);
    atomicAdd(&stat[640 + t], red[128 + t]);
  }
}

// ---------------- PASS2: CSR gather-reduce of BN2+ReLU(Y2), non-atomic ----------

template <int ADD>
__global__ __launch_bounds__(256) void k_agg2(
    const unsigned short* __restrict__ Y2, const int* __restrict__ off,
    const int* __restrict__ lst, const float* __restrict__ stat,
    const float* __restrict__ dinv, float* __restrict__ agg) {
  const int n = blockIdx.x * 4 + (threadIdx.x >> 6);
  const int lane = threadIdx.x & 63;
  if (n >= NN) return;
  const int o0 = off[n], o1 = off[n + 1];
  const float sc0 = stat[768 + 2 * lane], sc1 = stat[768 + 2 * lane + 1];
  const float sh0 = stat[896 + 2 * lane], sh1 = stat[896 + 2 * lane + 1];
  float a0 = 0.f, a1 = 0.f;
  for (int o = o0; o < o1; ++o) {
    const int e = lst[o];
    const unsigned int pw = ((const unsigned int*)(Y2 + (size_t)e * EMBD))[lane];
    a0 += fmaxf(fmaf(__uint_as_float(pw << 16), sc0, sh0), 0.f);
    a1 += fmaxf(fmaf(__uint_as_float(pw & 0xffff0000u), sc1, sh1), 0.f);
  }
  const float d = dinv[n];
  float2 out;
  if (ADD) {
    const float2 prev = ((const float2*)(agg + (size_t)n * EMBD))[lane];
    out.x = prev.x + a0 * d;
    out.y = prev.y + a1 * d;
  } else {
    out.x = a0 * d;
    out.y = a1 * d;
  }
  ((float2*)(agg + (size_t)n * EMBD))[lane] = out;
}

// ---------------- node update GEMM ----------------

template <int NK, bool SWZ>
__device__ __forceinline__ void gemm_g(const unsigned short* Ab, const int sa,
                                       const unsigned short* __restrict__ Wt,
                                       const int K, const int m, const int kg,
                                       const int w, f32x4 acc[4][2]) {
  const int n0 = w * 32 + m, n1 = n0 + 16;
#pragma unroll
  for (int ks = 0; ks < NK; ++ks) {
    const int koff = ks * 32 + kg * 8;
    const int aoff = SWZ ? physch(koff >> 3, m) * 8 : koff;
    const bf16x8 b0 = *(const bf16x8*)&Wt[(size_t)n0 * K + koff];
    const bf16x8 b1 = *(const bf16x8*)&Wt[(size_t)n1 * K + koff];
#pragma unroll
    for (int mt = 0; mt < 4; ++mt) {
      const bf16x8 a = *(const bf16x8*)&Ab[(mt * 16 + m) * sa + aoff];
      acc[mt][0] = MFMA16(a, b0, acc[mt][0]);
      acc[mt][1] = MFMA16(a, b1, acc[mt][1]);
    }
  }
}

__device__ __forceinline__ void stats_epi64(const f32x4 acc[4][2], float* red,
                                            float* __restrict__ statg, const int t,
                                            const int m, const int kg, const int w) {
#pragma unroll
  for (int nt = 0; nt < 2; ++nt) {
    float s = 0.f, q = 0.f;
#pragma unroll
    for (int mt = 0; mt < 4; ++mt)
#pragma unroll
      for (int r = 0; r < 4; ++r) {
        const float v = acc[mt][nt][r];
        s += v;
        q += v * v;
      }
    s += __shfl_xor(s, 16); s += __shfl_xor(s, 32);
    q += __shfl_xor(q, 16); q += __shfl_xor(q, 32);
    if (kg == 0) {
      const int c = w * 32 + nt * 16 + m;
      red[c] = s;
      red[128 + c] = q;
    }
  }
  __syncthreads();
  if (t < 128) {
    atomicAdd(&statg[t], red[t]);
    atomicAdd(&statg[128 + t], red[128 + t]);
  }
}

__global__ __launch_bounds__(256) void k_node(
    const float* __restrict__ nd, float* __restrict__ ag,
    const unsigned short* __restrict__ Wt, float* __restrict__ stat) {
  __shared__ __align__(16) unsigned short Ab[64 * SA1];
  __shared__ float red[256];
  const int t = threadIdx.x;
  const int n0 = blockIdx.x * 64;
  {
    const int r = t >> 2, sub = t & 3;
    const int row = n0 + r;
    unsigned short* drow = &Ab[r * SA1];
#pragma unroll
    for (int q = 0; q < 8; ++q) {
      const int c4 = sub + q * 4;
      float4 va;
      if (row < NN) {
        va = ((const float4*)(nd + (size_t)row * EMBD))[c4];
        const float4 vb = ((const float4*)(ag + (size_t)row * EMBD))[c4];
        va.x += vb.x; va.y += vb.y; va.z += vb.z; va.w += vb.w;
      } else {
        va.x = va.y = va.z = va.w = 0.f;
      }
      short4 b;
      b.x = (short)f2bf(va.x); b.y = (short)f2bf(va.y);
      b.z = (short)f2bf(va.z); b.w = (short)f2bf(va.w);
      *(short4*)&drow[c4 * 4] = b;
    }
  }
  __syncthreads();
  const int lane = t & 63, w = t >> 6, m = lane & 15, kg = lane >> 4;
  const f32x4 zz = {0.f, 0.f, 0.f, 0.f};
  f32x4 acc[4][2] = {{zz, zz}, {zz, zz}, {zz, zz}, {zz, zz}};
  gemm_g<4, false>(Ab, SA1, Wt, EMBD, m, kg, w, acc);
#pragma unroll
  for (int nt = 0; nt < 2; ++nt) {
    const int c = w * 32 + nt * 16 + m;
#pragma unroll
    for (int mt = 0; mt < 4; ++mt)
#pragma unroll
      for (int r = 0; r < 4; ++r) {
        const int row = n0 + mt * 16 + kg * 4 + r;
        if (row < NN) ag[(size_t)row * EMBD + c] = acc[mt][nt][r];
      }
  }
  stats_epi64(acc, red, stat, t, m, kg, w);
}

// ---------------- BN finalize / node residual ----------------

__global__ void k_finalize(float* __restrict__ statbase, const float* __restrict__ g,
                           const float* __restrict__ be, float cnt) {
  const int t = threadIdx.x;
  if (t < EMBD) {
    const float s = statbase[t], sq = statbase[EMBD + t];
    const float m = s / cnt;
    float v = sq / cnt - m * m;
    v = fmaxf(v, 0.f);
    const float rs = rsqrtf(v + EPSV);
    const float sc = g[t] * rs;
    statbase[256 + t] = sc;
    statbase[384 + t] = be[t] - m * sc;
    statbase[t] = 0.f;
    statbase[EMBD + t] = 0.f;
  }
}

__global__ void k_update(float* __restrict__ nd, unsigned short* __restrict__ xb,
                         const float* __restrict__ Z, const float* __restrict__ stat) {
  const float* sc = stat + 256;
  const float* sh = stat + 384;
  const int total = NN * EMBD / 4;
  for (int i = blockIdx.x * blockDim.x + threadIdx.x; i < total;
       i += gridDim.x * blockDim.x) {
    const int c4 = i & 31;
    const float4 v = ((const float4*)Z)[i];
    const float4 s4 = ((const float4*)sc)[c4];
    const float4 h4 = ((const float4*)sh)[c4];
    float4 nv = ((float4*)nd)[i];
    nv.x += fmaxf(fmaf(v.x, s4.x, h4.x), 0.f);
    nv.y += fmaxf(fmaf(v.y, s4.y, h4.y), 0.f);
    nv.z += fmaxf(fmaf(v.z, s4.z, h4.z), 0.f);
    nv.w += fmaxf(fmaf(v.w, s4.w, h4.w), 0.f);
    ((float4*)nd)[i] = nv;
    short4 b;
    b.x = (short)f2bf(nv.x); b.y = (short)f2bf(nv.y);
    b.z = (short)f2bf(nv.z); b.w = (short)f2bf(nv.w);
    *(short4*)&xb[(size_t)i * 4] = b;
  }
}

// ---------------- launch ----------------

extern "C" void kernel_launch(void* const* d_in, const int* in_sizes, int n_in,
                              void* d_out, int out_size, void* d_ws, size_t ws_size,
                              hipStream_t stream) {
  const float* in_nodes = (const float*)d_in[0];
  const void* edges = d_in[1];
  const float* ea = (const float*)d_in[2];
  const float* fW = (const float*)d_in[3];
  const float* fg = (const float*)d_in[5];
  const float* fbe = (const float*)d_in[6];
  const float* p_[8];
  const float* c_[8];
  for (int i = 0; i < 8; ++i) {
    p_[i] = (const float*)d_in[7 + i];
    c_[i] = (const float*)d_in[15 + i];
  }
  float* nodes = (float*)d_out;

  char* base = (char*)d_ws;
  size_t cur = 0;
  auto take = [&](size_t bytes) -> void* {
    void* p = base + cur;
    cur = (cur + bytes + 255) & ~(size_t)255;
    return p;
  };
  float* agg = (float*)take((size_t)NN * EMBD * 4);                   // 25.6 MB
  unsigned short* xb = (unsigned short*)take((size_t)NN * EMBD * 2);  // 12.8 MB
  int* src = (int*)take(EE * 4);
  int* dst = (int*)take(EE * 4);
  int* lstp = (int*)take(EE * 4);
  int* lstc = (int*)take(EE * 4);
  int* offp = (int*)take((NN + 1) * 4);
  int* offc = (int*)take((NN + 1) * 4);
  int* curp = (int*)take(NN * 4);
  int* curc = (int*)take(NN * 4);
  float* dinvp = (float*)take(NN * 4);
  float* dinvc = (float*)take(NN * 4);
  float* stat = (float*)take(1024 * 4);
  int* flag = (int*)take(4);
  unsigned short* pW1t = (unsigned short*)take((size_t)EMBD * KIN * 2);
  unsigned short* pW2t = (unsigned short*)take((size_t)EMBD * EMBD * 2);
  unsigned short* cW1t = (unsigned short*)take((size_t)EMBD * KIN * 2);
  unsigned short* cW2t = (unsigned short*)take((size_t)EMBD * EMBD * 2);
  unsigned short* fWt = (unsigned short*)take((size_t)EMBD * EMBD * 2);
  unsigned short* Y1 = (unsigned short*)take((size_t)EE * EMBD * 2);  // 102.4 MB
  // total ~149 MB (round-4 proved >=152 MB available)

  k_zeroi<<<64, 256, 0, stream>>>((int*)stat, 1024);
  k_zeroi<<<128, 256, 0, stream>>>(curp, NN);
  k_zeroi<<<128, 256, 0, stream>>>(curc, NN);
  k_detect<<<1, 256, 0, stream>>>((const long long*)edges, flag);
  k_convert<<<1024, 256, 0, stream>>>(edges, flag, src, dst);
  k_count<<<1024, 256, 0, stream>>>(src, dst, curp, curc);
  k_dinv<<<128, 256, 0, stream>>>(curp, curc, dinvp, dinvc);
  k_scan<<<2, 1024, 0, stream>>>(curp, curc, offp, offc);
  k_copycur<<<128, 256, 0, stream>>>(offp, offc, curp, curc);
  k_scatter<<<1024, 256, 0, stream>>>(src, dst, curp, curc, lstp, lstc);
  k_initnodes<<<2048, 256, 0, stream>>>(in_nodes, nodes, xb);
  k_prepW<<<(KIN * EMBD + 255) / 256, 256, 0, stream>>>(p_[0], pW1t, KIN);
  k_prepW<<<(EMBD * EMBD + 255) / 256, 256, 0, stream>>>(p_[4], pW2t, EMBD);
  k_prepW<<<(KIN * EMBD + 255) / 256, 256, 0, stream>>>(c_[0], cW1t, KIN);
  k_prepW<<<(EMBD * EMBD + 255) / 256, 256, 0, stream>>>(c_[4], cW2t, EMBD);
  k_prepW<<<(EMBD * EMBD + 255) / 256, 256, 0, stream>>>(fW, fWt, EMBD);

  const int NB = (NN + 63) / 64;  // 782

  for (int it = 0; it < NITERS; ++it) {
    // parent phase: idx_i = dst, idx_j = src
    k_pass0<<<G0, 256, 0, stream>>>(xb, dst, src, ea, pW1t, stat, Y1);
    k_finalize<<<1, 128, 0, stream>>>(stat, p_[2], p_[3], (float)EE);
    k_pass1<<<G1, 256, 0, stream>>>(pW2t, stat, Y1);
    k_finalize<<<1, 128, 0, stream>>>(stat + 512, p_[6], p_[7], (float)EE);
    k_agg2<0><<<NN / 4, 256, 0, stream>>>(Y1, offp, lstp, stat, dinvp, agg);
    // child phase: idx_i = src, idx_j = dst
    k_pass0<<<G0, 256, 0, stream>>>(xb, src, dst, ea, cW1t, stat, Y1);
    k_finalize<<<1, 128, 0, stream>>>(stat, c_[2], c_[3], (float)EE);
    k_pass1<<<G1, 256, 0, stream>>>(cW2t, stat, Y1);
    k_finalize<<<1, 128, 0, stream>>>(stat + 512, c_[6], c_[7], (float)EE);
    k_agg2<1><<<NN / 4, 256, 0, stream>>>(Y1, offc, lstc, stat, dinvc, agg);
    // node update
    k_node<<<NB, 256, 0, stream>>>(nodes, agg, fWt, stat);
    k_finalize<<<1, 128, 0, stream>>>(stat, fg, fbe, (float)NN);
    k_update<<<2048, 256, 0, stream>>>(nodes, xb, agg, stat);
  }
}